// Round 1
// baseline (1016.615 us; speedup 1.0000x reference)
//
#include <hip/hip_runtime.h>
#include <math.h>

#define TB 256
static const int Bb = 32, Ls = 512, Dd = 768, Cc = 97;

// ---- block-wide sum (256 threads = 4 waves), result broadcast to all threads
__device__ __forceinline__ float blk_sum(float v, float* sh4) {
#pragma unroll
    for (int o = 32; o > 0; o >>= 1) v += __shfl_down(v, o, 64);
    int lane = threadIdx.x & 63, w = threadIdx.x >> 6;
    if (lane == 0) sh4[w] = v;
    __syncthreads();
    float r = sh4[0] + sh4[1] + sh4[2] + sh4[3];
    __syncthreads();
    return r;
}

// ---- fp32 SGEMM: C[M,N] = A[M,K] @ W[K,N] (+bias[N]); N%64==0, K%16==0
__global__ __launch_bounds__(256) void sgemm_kernel(
        const float* __restrict__ A, const float* __restrict__ W,
        const float* __restrict__ bias, float* __restrict__ C,
        int M, int N, int K) {
    __shared__ float As[16][64];
    __shared__ float Ws[16][64];
    int tid = threadIdx.x;
    int tx = tid & 15, ty = tid >> 4;
    int bn = blockIdx.x * 64, bm = blockIdx.y * 64;
    int arow = tid >> 2, akq = (tid & 3) << 2;   // A tile: 64 rows x 16 k (float4)
    int wrow = tid >> 4, wcol = (tid & 15) << 2; // W tile: 16 k x 64 cols (float4)
    int gar = bm + arow;
    bool aval = gar < M;
    const float* Ap = A + (size_t)gar * K + akq;
    const float* Wp = W + (size_t)wrow * N + bn + wcol;
    float acc[4][4] = {{0.f}};
    for (int k0 = 0; k0 < K; k0 += 16) {
        float4 a4 = make_float4(0.f, 0.f, 0.f, 0.f);
        if (aval) a4 = *(const float4*)(Ap + k0);
        float4 w4 = *(const float4*)(Wp + (size_t)k0 * N);
        __syncthreads();
        As[akq + 0][arow] = a4.x; As[akq + 1][arow] = a4.y;
        As[akq + 2][arow] = a4.z; As[akq + 3][arow] = a4.w;
        *(float4*)&Ws[wrow][wcol] = w4;
        __syncthreads();
#pragma unroll
        for (int kk = 0; kk < 16; ++kk) {
            float4 a = *(const float4*)&As[kk][ty << 2];
            float4 b = *(const float4*)&Ws[kk][tx << 2];
            acc[0][0] += a.x * b.x; acc[0][1] += a.x * b.y; acc[0][2] += a.x * b.z; acc[0][3] += a.x * b.w;
            acc[1][0] += a.y * b.x; acc[1][1] += a.y * b.y; acc[1][2] += a.y * b.z; acc[1][3] += a.y * b.w;
            acc[2][0] += a.z * b.x; acc[2][1] += a.z * b.y; acc[2][2] += a.z * b.z; acc[2][3] += a.z * b.w;
            acc[3][0] += a.w * b.x; acc[3][1] += a.w * b.y; acc[3][2] += a.w * b.z; acc[3][3] += a.w * b.w;
        }
    }
    int gc = bn + (tx << 2);
    float4 bz = make_float4(0.f, 0.f, 0.f, 0.f);
    if (bias) bz = *(const float4*)(bias + gc);
#pragma unroll
    for (int i = 0; i < 4; ++i) {
        int gr = bm + (ty << 2) + i;
        if (gr < M) {
            float4 r;
            r.x = acc[i][0] + bz.x; r.y = acc[i][1] + bz.y;
            r.z = acc[i][2] + bz.z; r.w = acc[i][3] + bz.w;
            *(float4*)(C + (size_t)gr * N + gc) = r;
        }
    }
}

// ---- broadcast p0 (C,D) over batch -> P (B,C,D)
__global__ void bcast_kernel(const float* __restrict__ p0, float* __restrict__ P, int total) {
    int i = blockIdx.x * TB + threadIdx.x;
    if (i < total) P[i] = p0[i % (Cc * Dd)];
}

// ---- kvec[idx][d] = sum_j kw[idx][d][j] * sw[idx][768+j]   (all 4 (li,ra) at once)
__global__ void kvec_kernel(const float* __restrict__ kw, const float* __restrict__ sw,
                            float* __restrict__ kvecs) {
    __shared__ float sh4[4];
    int idx = blockIdx.y;  // li*2+ra
    int d = blockIdx.x;
    const float* row = kw + ((size_t)idx * Dd + d) * Dd;
    const float* swk = sw + (size_t)idx * 2 * Dd + Dd;
    float t = 0.f;
    for (int j = threadIdx.x; j < Dd; j += TB) t += row[j] * swk[j];
    t = blk_sum(t, sh4);
    if (threadIdx.x == 0) kvecs[(size_t)idx * Dd + d] = t;
}

// ---- out[r] = A[r,:] . v   (rows of length 768)
__global__ void rowdot_kernel(const float* __restrict__ A, const float* __restrict__ v,
                              float* __restrict__ outv) {
    __shared__ float sh4[4];
    int r = blockIdx.x;
    const float* row = A + (size_t)r * Dd;
    float t = 0.f;
    for (int j = threadIdx.x; j < Dd; j += TB) t += row[j] * v[j];
    t = blk_sum(t, sh4);
    if (threadIdx.x == 0) outv[r] = t;
}

// ---- per-batch softmax over N kv positions (optional mask, length N)
__global__ void softmax_kernel(const float* __restrict__ ks, const int* __restrict__ mask,
                               float* __restrict__ w, int N) {
    __shared__ float sh4[4];
    int b = blockIdx.x;
    const float* row = ks + (size_t)b * N;
    const int* mrow = mask ? mask + (size_t)b * N : nullptr;
    float mx = -3.0e38f;
    for (int n = threadIdx.x; n < N; n += TB) {
        float v = row[n];
        if (mrow && mrow[n] == 0) v = -1e9f;
        mx = fmaxf(mx, v);
    }
#pragma unroll
    for (int o = 32; o > 0; o >>= 1) mx = fmaxf(mx, __shfl_down(mx, o, 64));
    if ((threadIdx.x & 63) == 0) sh4[threadIdx.x >> 6] = mx;
    __syncthreads();
    mx = fmaxf(fmaxf(sh4[0], sh4[1]), fmaxf(sh4[2], sh4[3]));
    __syncthreads();
    float s = 0.f;
    for (int n = threadIdx.x; n < N; n += TB) {
        float v = row[n];
        if (mrow && mrow[n] == 0) v = -1e9f;
        s += expf(v - mx);
    }
    s = blk_sum(s, sh4);
    float inv = 1.f / s;
    for (int n = threadIdx.x; n < N; n += TB) {
        float v = row[n];
        if (mrow && mrow[n] == 0) v = -1e9f;
        w[(size_t)b * N + n] = expf(v - mx) * inv;
    }
}

// ---- xa[b,d] = sum_n w[b,n] * Xkv[b,n,d]
__global__ void xa_kernel(const float* __restrict__ Xkv, const float* __restrict__ wts,
                          float* __restrict__ xa, int N) {
    int b = blockIdx.y;
    int d = blockIdx.x * TB + threadIdx.x;
    const float* xb = Xkv + (size_t)b * N * Dd + d;
    const float* wb = wts + (size_t)b * N;
    float acc = 0.f;
    for (int n = 0; n < N; ++n) acc += wb[n] * xb[(size_t)n * Dd];
    xa[(size_t)b * Dd + d] = acc;
}

// ---- C[m,j] = A[m,:] @ W[:,j] + bias[j], M=32 rows (grid.y = m)
__global__ void mm32_kernel(const float* __restrict__ A, const float* __restrict__ W,
                            const float* __restrict__ bias, float* __restrict__ Cout) {
    int m = blockIdx.y;
    int j = blockIdx.x * TB + threadIdx.x;
    float acc = bias ? bias[j] : 0.f;
    const float* arow = A + (size_t)m * Dd;
    for (int d = 0; d < Dd; ++d) acc += arow[d] * W[(size_t)d * Dd + j];
    Cout[(size_t)m * Dd + j] = acc;
}

// ---- fused gate + residual update (+ optional ks for the NEXT RA via kvec2):
//   t = Psrc[r,:]·(gw0+gw1); g = sigmoid(t + sav[b] + gb)
//   Pdst[r,:] = g*av[b,:] + 2*Psrc[r,:];  ks2[r] = Pdst[r,:]·kvec2
__global__ void gate_kernel(const float* __restrict__ Psrc, float* __restrict__ Pdst,
                            const float* __restrict__ av, const float* __restrict__ savb,
                            const float* __restrict__ gw, const float* __restrict__ gbp,
                            const float* __restrict__ kvec2, float* __restrict__ ks2,
                            int Mq) {
    __shared__ float sh4[4];
    int r = blockIdx.x;
    int b = r / Mq;
    const float* prow = Psrc + (size_t)r * Dd;
    float pv[3];
    float t = 0.f;
#pragma unroll
    for (int i = 0; i < 3; ++i) {
        int d = threadIdx.x + i * TB;
        float p = prow[d];
        pv[i] = p;
        t += p * (gw[d] + gw[Dd + d]);
    }
    t = blk_sum(t, sh4);
    float g = 1.f / (1.f + expf(-(t + savb[b] + gbp[0])));
    float t2 = 0.f;
#pragma unroll
    for (int i = 0; i < 3; ++i) {
        int d = threadIdx.x + i * TB;
        float xn = g * av[(size_t)b * Dd + d] + 2.f * pv[i];
        Pdst[(size_t)r * Dd + d] = xn;
        if (kvec2) t2 += xn * kvec2[d];
    }
    if (kvec2) {
        t2 = blk_sum(t2, sh4);
        if (threadIdx.x == 0) ks2[r] = t2;
    }
}

// ---- 1/sum(pos1), 1/sum(pos2) per batch
__global__ void pooldenom_kernel(const float* __restrict__ pos1, const float* __restrict__ pos2,
                                 float* __restrict__ invb) {
    __shared__ float sh4[4];
    int b = blockIdx.x;
    float s1 = 0.f, s2 = 0.f;
    for (int l = threadIdx.x; l < Ls; l += TB) {
        s1 += pos1[(size_t)b * Ls + l];
        s2 += pos2[(size_t)b * Ls + l];
    }
    s1 = blk_sum(s1, sh4);
    s2 = blk_sum(s2, sh4);
    if (threadIdx.x == 0) { invb[b] = 1.f / s1; invb[32 + b] = 1.f / s2; }
}

// ---- e1[b,d], e2[b,d] masked-average pools over L
__global__ void poole_kernel(const float* __restrict__ X, const float* __restrict__ pos1,
                             const float* __restrict__ pos2, const float* __restrict__ invb,
                             float* __restrict__ e) {
    int b = blockIdx.y;
    int d = blockIdx.x * TB + threadIdx.x;
    float a1 = 0.f, a2 = 0.f;
    const float* xb = X + (size_t)b * Ls * Dd + d;
    for (int l = 0; l < Ls; ++l) {
        float xv = xb[(size_t)l * Dd];
        a1 += xv * pos1[(size_t)b * Ls + l];
        a2 += xv * pos2[(size_t)b * Ls + l];
    }
    e[(size_t)b * Dd + d] = a1 * invb[b];
    e[(size_t)(Bb + b) * Dd + d] = a2 * invb[32 + b];
}

// ---- ge[b,j] = e1[b]:@W1 + e2[b]:@W2 + fc1_b   (W1 = fc1w rows 768..1535, W2 = 1536..2303)
__global__ void ge_kernel(const float* __restrict__ e, const float* __restrict__ fc1w,
                          const float* __restrict__ fc1b, float* __restrict__ ge) {
    int b = blockIdx.y;
    int j = blockIdx.x * TB + threadIdx.x;
    const float* e1 = e + (size_t)b * Dd;
    const float* e2 = e + (size_t)(Bb + b) * Dd;
    float acc = fc1b[j];
    for (int d = 0; d < Dd; ++d) {
        acc += e1[d] * fc1w[(size_t)(Dd + d) * Dd + j]
             + e2[d] * fc1w[(size_t)(2 * Dd + d) * Dd + j];
    }
    ge[(size_t)b * Dd + j] = acc;
}

// ---- h = tanh(h + ge[b])
__global__ void addtanh_kernel(float* __restrict__ h, const float* __restrict__ ge) {
    size_t i = (size_t)blockIdx.x * TB + threadIdx.x;
    if (i < (size_t)Bb * Cc * Dd) {
        int r = (int)(i / Dd);
        int j = (int)(i - (size_t)r * Dd);
        int b = r / Cc;
        h[i] = tanhf(h[i] + ge[(size_t)b * Dd + j]);
    }
}

// ---- logits[r] = sigmoid(h[r]:·fc2w + fc2b)
__global__ void logits_kernel(const float* __restrict__ h, const float* __restrict__ fc2w,
                              const float* __restrict__ fc2b, float* __restrict__ out) {
    __shared__ float sh4[4];
    int r = blockIdx.x;
    const float* row = h + (size_t)r * Dd;
    float t = 0.f;
    for (int j = threadIdx.x; j < Dd; j += TB) t += row[j] * fc2w[j];
    t = blk_sum(t, sh4);
    if (threadIdx.x == 0) out[r] = 1.f / (1.f + expf(-(t + fc2b[0])));
}

// ---- pred[b] = (float) argmax_c logits[b,c]  (first max, like np/jnp argmax)
__global__ void argmax_kernel(const float* __restrict__ lg, float* __restrict__ pred) {
    int b = threadIdx.x;
    if (b < Bb) {
        const float* row = lg + (size_t)b * Cc;
        float best = row[0];
        int bi = 0;
        for (int c = 1; c < Cc; ++c) {
            float v = row[c];
            if (v > best) { best = v; bi = c; }
        }
        pred[b] = (float)bi;
    }
}

extern "C" void kernel_launch(void* const* d_in, const int* in_sizes, int n_in,
                              void* d_out, int out_size, void* d_ws, size_t ws_size,
                              hipStream_t stream) {
    const float* x0    = (const float*)d_in[0];
    const float* pos1  = (const float*)d_in[1];
    const float* pos2  = (const float*)d_in[2];
    const int*   mask  = (const int*)d_in[3];
    const float* emb   = (const float*)d_in[4];
    const float* rel_w = (const float*)d_in[5];
    const float* rel_b = (const float*)d_in[6];
    // d_in[7] qw, d_in[8] qb: provably dead (softmax is query-shift invariant)
    const float* kw    = (const float*)d_in[9];
    // d_in[10] kb: row-constant in score -> softmax-invariant, dead
    const float* vw    = (const float*)d_in[11];
    const float* vb    = (const float*)d_in[12];
    const float* sw    = (const float*)d_in[13];
    // d_in[14] sb: row-constant -> softmax-invariant, dead
    const float* gw    = (const float*)d_in[15];
    const float* gb    = (const float*)d_in[16];
    const float* fc1w  = (const float*)d_in[17];
    const float* fc1b  = (const float*)d_in[18];
    const float* fc2w  = (const float*)d_in[19];
    const float* fc2b  = (const float*)d_in[20];
    float* out = (float*)d_out;

    float* ws = (float*)d_ws;
    size_t off = 0;
    float* Pw    = ws + off; off += (size_t)Bb * Cc * Dd;   // current p (B,C,D)
    float* Xw    = ws + off; off += (size_t)Bb * Ls * Dd;   // current x (B,L,D)
    float* p0b   = ws + off; off += (size_t)Cc * Dd;
    float* kvecs = ws + off; off += (size_t)4 * Dd;         // kw@sw_k for all 4 (li,ra)
    float* ksb   = ws + off; off += (size_t)Bb * Ls;        // score row-terms
    float* awb   = ws + off; off += (size_t)Bb * Ls;        // softmax weights
    float* xab   = ws + off; off += (size_t)Bb * Dd;        // attn-weighted input
    float* avb   = ws + off; off += (size_t)Bb * Dd;        // xa@vw+vb
    float* savb  = ws + off; off += 64;                     // av . gw0
    float* invb  = ws + off; off += 64;                     // pool denoms
    float* eb    = ws + off; off += (size_t)2 * Bb * Dd;    // e1,e2
    float* geb   = ws + off; off += (size_t)Bb * Dd;        // e-part of fc1
    float* hb    = ws + off; off += (size_t)Bb * Cc * Dd;   // fc1 hidden

    // p0 = emb @ rel_w + rel_b; broadcast over batch
    {
        dim3 g(Dd / 64, (Cc + 63) / 64);
        sgemm_kernel<<<g, TB, 0, stream>>>(emb, rel_w, rel_b, p0b, Cc, Dd, Dd);
    }
    {
        int tot = Bb * Cc * Dd;
        bcast_kernel<<<(tot + TB - 1) / TB, TB, 0, stream>>>(p0b, Pw, tot);
    }
    kvec_kernel<<<dim3(Dd, 4), TB, 0, stream>>>(kw, sw, kvecs);

    const float* xsrc = x0;
    for (int li = 0; li < 2; ++li) {
        int i1 = li * 2 + 0, i2 = li * 2 + 1;
        const float* vw1 = vw + (size_t)i1 * Dd * Dd; const float* vb1 = vb + (size_t)i1 * Dd;
        const float* gw1 = gw + (size_t)i1 * 2 * Dd;  const float* gb1 = gb + i1;
        const float* vw2 = vw + (size_t)i2 * Dd * Dd; const float* vb2 = vb + (size_t)i2 * Dd;
        const float* gw2 = gw + (size_t)i2 * 2 * Dd;  const float* gb2 = gb + i2;

        // ---- RA1: update x; kv = P (N=C), no mask
        rowdot_kernel<<<Bb * Cc, TB, 0, stream>>>(Pw, kvecs + (size_t)i1 * Dd, ksb);
        softmax_kernel<<<Bb, TB, 0, stream>>>(ksb, nullptr, awb, Cc);
        xa_kernel<<<dim3(Dd / TB, Bb), TB, 0, stream>>>(Pw, awb, xab, Cc);
        mm32_kernel<<<dim3(Dd / TB, Bb), TB, 0, stream>>>(xab, vw1, vb1, avb);
        rowdot_kernel<<<Bb, TB, 0, stream>>>(avb, gw1, savb);
        // x_new = g*av1 + 2x ; fused: ks2[r] = x_new . kvec2 for the next RA
        gate_kernel<<<Bb * Ls, TB, 0, stream>>>(xsrc, Xw, avb, savb, gw1, gb1,
                                                kvecs + (size_t)i2 * Dd, ksb, Ls);
        xsrc = Xw;

        // ---- RA2: update p; kv = new x (N=L), masked
        softmax_kernel<<<Bb, TB, 0, stream>>>(ksb, mask, awb, Ls);
        xa_kernel<<<dim3(Dd / TB, Bb), TB, 0, stream>>>(Xw, awb, xab, Ls);
        mm32_kernel<<<dim3(Dd / TB, Bb), TB, 0, stream>>>(xab, vw2, vb2, avb);
        rowdot_kernel<<<Bb, TB, 0, stream>>>(avb, gw2, savb);
        gate_kernel<<<Bb * Cc, TB, 0, stream>>>(Pw, Pw, avb, savb, gw2, gb2,
                                                nullptr, nullptr, Cc);
    }

    // pooling + classifier
    pooldenom_kernel<<<Bb, TB, 0, stream>>>(pos1, pos2, invb);
    poole_kernel<<<dim3(Dd / TB, Bb), TB, 0, stream>>>(Xw, pos1, pos2, invb, eb);
    ge_kernel<<<dim3(Dd / TB, Bb), TB, 0, stream>>>(eb, fc1w, fc1b, geb);
    {
        dim3 g(Dd / 64, (Bb * Cc + 63) / 64);
        sgemm_kernel<<<g, TB, 0, stream>>>(Pw, fc1w, nullptr, hb, Bb * Cc, Dd, Dd);
    }
    {
        size_t tot = (size_t)Bb * Cc * Dd;
        addtanh_kernel<<<(int)((tot + TB - 1) / TB), TB, 0, stream>>>(hb, geb);
    }
    logits_kernel<<<Bb * Cc, TB, 0, stream>>>(hb, fc2w, fc2b, out);
    argmax_kernel<<<1, 64, 0, stream>>>(out, out + Bb * Cc);
}

// Round 2
// 561.424 us; speedup vs baseline: 1.8108x; 1.8108x over previous
//
#include <hip/hip_runtime.h>
#include <math.h>

#define TB 256
static const int Bb = 32, Ls = 512, Dd = 768, Cc = 97;

// ---- block-wide sum, 256 threads (4 waves)
__device__ __forceinline__ float blk_sum4(float v, float* sh) {
#pragma unroll
    for (int o = 32; o > 0; o >>= 1) v += __shfl_down(v, o, 64);
    int lane = threadIdx.x & 63, w = threadIdx.x >> 6;
    if (lane == 0) sh[w] = v;
    __syncthreads();
    float r = sh[0] + sh[1] + sh[2] + sh[3];
    __syncthreads();
    return r;
}

// ---- block-wide sum, 192 threads (3 waves)
__device__ __forceinline__ float blk_sum3(float v, float* sh) {
#pragma unroll
    for (int o = 32; o > 0; o >>= 1) v += __shfl_down(v, o, 64);
    int lane = threadIdx.x & 63, w = threadIdx.x >> 6;
    if (lane == 0) sh[w] = v;
    __syncthreads();
    float r = sh[0] + sh[1] + sh[2];
    __syncthreads();
    return r;
}

// ---- fp32 SGEMM: C[M,N] = A[M,K] @ W[K,N] (+bias[N]); N%64==0, K%16==0
__global__ __launch_bounds__(256) void sgemm_kernel(
        const float* __restrict__ A, const float* __restrict__ W,
        const float* __restrict__ bias, float* __restrict__ C,
        int M, int N, int K) {
    __shared__ float As[16][64];
    __shared__ float Ws[16][64];
    int tid = threadIdx.x;
    int tx = tid & 15, ty = tid >> 4;
    int bn = blockIdx.x * 64, bm = blockIdx.y * 64;
    int arow = tid >> 2, akq = (tid & 3) << 2;
    int wrow = tid >> 4, wcol = (tid & 15) << 2;
    int gar = bm + arow;
    bool aval = gar < M;
    const float* Ap = A + (size_t)gar * K + akq;
    const float* Wp = W + (size_t)wrow * N + bn + wcol;
    float acc[4][4] = {{0.f}};
    for (int k0 = 0; k0 < K; k0 += 16) {
        float4 a4 = make_float4(0.f, 0.f, 0.f, 0.f);
        if (aval) a4 = *(const float4*)(Ap + k0);
        float4 w4 = *(const float4*)(Wp + (size_t)k0 * N);
        __syncthreads();
        As[akq + 0][arow] = a4.x; As[akq + 1][arow] = a4.y;
        As[akq + 2][arow] = a4.z; As[akq + 3][arow] = a4.w;
        *(float4*)&Ws[wrow][wcol] = w4;
        __syncthreads();
#pragma unroll
        for (int kk = 0; kk < 16; ++kk) {
            float4 a = *(const float4*)&As[kk][ty << 2];
            float4 b = *(const float4*)&Ws[kk][tx << 2];
            acc[0][0] += a.x * b.x; acc[0][1] += a.x * b.y; acc[0][2] += a.x * b.z; acc[0][3] += a.x * b.w;
            acc[1][0] += a.y * b.x; acc[1][1] += a.y * b.y; acc[1][2] += a.y * b.z; acc[1][3] += a.y * b.w;
            acc[2][0] += a.z * b.x; acc[2][1] += a.z * b.y; acc[2][2] += a.z * b.z; acc[2][3] += a.z * b.w;
            acc[3][0] += a.w * b.x; acc[3][1] += a.w * b.y; acc[3][2] += a.w * b.z; acc[3][3] += a.w * b.w;
        }
    }
    int gc = bn + (tx << 2);
    float4 bz = make_float4(0.f, 0.f, 0.f, 0.f);
    if (bias) bz = *(const float4*)(bias + gc);
#pragma unroll
    for (int i = 0; i < 4; ++i) {
        int gr = bm + (ty << 2) + i;
        if (gr < M) {
            float4 r;
            r.x = acc[i][0] + bz.x; r.y = acc[i][1] + bz.y;
            r.z = acc[i][2] + bz.z; r.w = acc[i][3] + bz.w;
            *(float4*)(C + (size_t)gr * N + gc) = r;
        }
    }
}

// ---- P[r,:]=p0[c,:], ks0[r]=P[r,:]·kvec0   (r = b*C + c); 192 threads
__global__ void bcast_row_kernel(const float* __restrict__ p0, float* __restrict__ P,
                                 const float* __restrict__ kvec0, float* __restrict__ ks0) {
    __shared__ float sh[3];
    int r = blockIdx.x, c = r % Cc;
    int d4 = threadIdx.x << 2;
    float4 p = *(const float4*)(p0 + (size_t)c * Dd + d4);
    *(float4*)(P + (size_t)r * Dd + d4) = p;
    float4 kv = *(const float4*)(kvec0 + d4);
    float t = p.x * kv.x + p.y * kv.y + p.z * kv.z + p.w * kv.w;
    t = blk_sum3(t, sh);
    if (threadIdx.x == 0) ks0[r] = t;
}

// ---- kvec[idx][d] = kw[idx][d][:] . sw[idx][768:]
__global__ void kvec_kernel(const float* __restrict__ kw, const float* __restrict__ sw,
                            float* __restrict__ kvecs) {
    __shared__ float sh[4];
    int idx = blockIdx.y, d = blockIdx.x;
    const float* row = kw + ((size_t)idx * Dd + d) * Dd;
    const float* swk = sw + (size_t)idx * 2 * Dd + Dd;
    float t = 0.f;
    for (int j = threadIdx.x; j < Dd; j += TB) t += row[j] * swk[j];
    t = blk_sum4(t, sh);
    if (threadIdx.x == 0) kvecs[(size_t)idx * Dd + d] = t;
}

// ---- out[r] = A[r,:] . v (small grids only: savb)
__global__ void rowdot_kernel(const float* __restrict__ A, const float* __restrict__ v,
                              float* __restrict__ outv) {
    __shared__ float sh[4];
    int r = blockIdx.x;
    const float* row = A + (size_t)r * Dd;
    float t = 0.f;
    for (int j = threadIdx.x; j < Dd; j += TB) t += row[j] * v[j];
    t = blk_sum4(t, sh);
    if (threadIdx.x == 0) outv[r] = t;
}

// ---- per-batch softmax over N kv positions; ALSO zero xab,avb rows for this b
__global__ void softmax_kernel(const float* __restrict__ ks, const int* __restrict__ mask,
                               float* __restrict__ w, int N,
                               float* __restrict__ xab, float* __restrict__ avb) {
    __shared__ float sh[4];
    int b = blockIdx.x;
    // zero accumulators for the upcoming atomic kernels
    for (int d = threadIdx.x; d < Dd; d += TB) {
        xab[(size_t)b * Dd + d] = 0.f;
        avb[(size_t)b * Dd + d] = 0.f;
    }
    const float* row = ks + (size_t)b * N;
    const int* mrow = mask ? mask + (size_t)b * N : nullptr;
    float mx = -3.0e38f;
    for (int n = threadIdx.x; n < N; n += TB) {
        float v = row[n];
        if (mrow && mrow[n] == 0) v = -1e9f;
        mx = fmaxf(mx, v);
    }
#pragma unroll
    for (int o = 32; o > 0; o >>= 1) mx = fmaxf(mx, __shfl_down(mx, o, 64));
    if ((threadIdx.x & 63) == 0) sh[threadIdx.x >> 6] = mx;
    __syncthreads();
    mx = fmaxf(fmaxf(sh[0], sh[1]), fmaxf(sh[2], sh[3]));
    __syncthreads();
    float s = 0.f;
    for (int n = threadIdx.x; n < N; n += TB) {
        float v = row[n];
        if (mrow && mrow[n] == 0) v = -1e9f;
        s += expf(v - mx);
    }
    s = blk_sum4(s, sh);
    float inv = 1.f / s;
    for (int n = threadIdx.x; n < N; n += TB) {
        float v = row[n];
        if (mrow && mrow[n] == 0) v = -1e9f;
        w[(size_t)b * N + n] = expf(v - mx) * inv;
    }
}

// ---- xa[b,:] += sum over this block's n-segment of w[b,n]*X[b,n,:]; 192 thr float4
__global__ void xa_kernel(const float* __restrict__ Xkv, const float* __restrict__ wts,
                          float* __restrict__ xa, int N, int rps) {
    int b = blockIdx.x, seg = blockIdx.y;
    int n0 = seg * rps, n1 = min(N, n0 + rps);
    int d4 = threadIdx.x << 2;
    const float* xb = Xkv + ((size_t)b * N + n0) * Dd + d4;
    const float* wb = wts + (size_t)b * N;
    float4 acc = make_float4(0.f, 0.f, 0.f, 0.f);
    for (int n = n0; n < n1; ++n) {
        float wn = wb[n];
        float4 xv = *(const float4*)(xb + (size_t)(n - n0) * Dd);
        acc.x += wn * xv.x; acc.y += wn * xv.y; acc.z += wn * xv.z; acc.w += wn * xv.w;
    }
    float* dst = xa + (size_t)b * Dd + d4;
    atomicAdd(dst + 0, acc.x); atomicAdd(dst + 1, acc.y);
    atomicAdd(dst + 2, acc.z); atomicAdd(dst + 3, acc.w);
}

// ---- av[b,j] += xa[b,dseg]·vw[dseg,j] (+vb[j] once); grid (3, 32, 4)
__global__ void mm32_kernel(const float* __restrict__ xa, const float* __restrict__ W,
                            const float* __restrict__ bias, float* __restrict__ av) {
    __shared__ float xs[192];
    int j = blockIdx.x * TB + threadIdx.x;
    int b = blockIdx.y, seg = blockIdx.z;
    if (threadIdx.x < 192) xs[threadIdx.x] = xa[(size_t)b * Dd + seg * 192 + threadIdx.x];
    __syncthreads();
    float acc = (seg == 0 && bias) ? bias[j] : 0.f;
    const float* wp = W + (size_t)(seg * 192) * Dd + j;
#pragma unroll 4
    for (int dd = 0; dd < 192; ++dd) acc += xs[dd] * wp[(size_t)dd * Dd];
    atomicAdd(&av[(size_t)b * Dd + j], acc);
}

// ---- fused gate + residual (+ optional next-RA ks); 192 threads, float4 rows
__global__ void gate_kernel(const float* __restrict__ Psrc, float* __restrict__ Pdst,
                            const float* __restrict__ av, const float* __restrict__ savb,
                            const float* __restrict__ gw, const float* __restrict__ gbp,
                            const float* __restrict__ kvec2, float* __restrict__ ks2,
                            int Mq) {
    __shared__ float sh[3];
    int r = blockIdx.x, b = r / Mq;
    int d4 = threadIdx.x << 2;
    float4 p = *(const float4*)(Psrc + (size_t)r * Dd + d4);
    float4 g0 = *(const float4*)(gw + d4);
    float4 g1 = *(const float4*)(gw + Dd + d4);
    float t = p.x * (g0.x + g1.x) + p.y * (g0.y + g1.y)
            + p.z * (g0.z + g1.z) + p.w * (g0.w + g1.w);
    t = blk_sum3(t, sh);
    float g = 1.f / (1.f + expf(-(t + savb[b] + gbp[0])));
    float4 a = *(const float4*)(av + (size_t)b * Dd + d4);
    float4 xn;
    xn.x = g * a.x + 2.f * p.x; xn.y = g * a.y + 2.f * p.y;
    xn.z = g * a.z + 2.f * p.z; xn.w = g * a.w + 2.f * p.w;
    *(float4*)(Pdst + (size_t)r * Dd + d4) = xn;
    if (kvec2) {
        float4 kv = *(const float4*)(kvec2 + d4);
        float t2 = xn.x * kv.x + xn.y * kv.y + xn.z * kv.z + xn.w * kv.w;
        t2 = blk_sum3(t2, sh);
        if (threadIdx.x == 0) ks2[r] = t2;
    }
}

// ---- per-batch pool denominators; ALSO zero eb (raw sums) and geb
__global__ void pooldenom_kernel(const float* __restrict__ pos1, const float* __restrict__ pos2,
                                 float* __restrict__ invb,
                                 float* __restrict__ eb, float* __restrict__ geb) {
    __shared__ float sh[4];
    int b = blockIdx.x;
    for (int d = threadIdx.x; d < Dd; d += TB) {
        eb[(size_t)b * Dd + d] = 0.f;
        eb[(size_t)(Bb + b) * Dd + d] = 0.f;
        geb[(size_t)b * Dd + d] = 0.f;
    }
    float s1 = 0.f, s2 = 0.f;
    for (int l = threadIdx.x; l < Ls; l += TB) {
        s1 += pos1[(size_t)b * Ls + l];
        s2 += pos2[(size_t)b * Ls + l];
    }
    s1 = blk_sum4(s1, sh);
    s2 = blk_sum4(s2, sh);
    if (threadIdx.x == 0) { invb[b] = 1.f / s1; invb[32 + b] = 1.f / s2; }
}

// ---- raw pooled sums over L-segment (scaled later in ge); 192 thr float4, atomic
__global__ void poole_kernel(const float* __restrict__ X, const float* __restrict__ pos1,
                             const float* __restrict__ pos2, float* __restrict__ eb, int rps) {
    int b = blockIdx.x, seg = blockIdx.y;
    int l0 = seg * rps, l1 = min(Ls, l0 + rps);
    int d4 = threadIdx.x << 2;
    const float* xb = X + ((size_t)b * Ls + l0) * Dd + d4;
    float4 a1 = make_float4(0.f, 0.f, 0.f, 0.f);
    float4 a2 = make_float4(0.f, 0.f, 0.f, 0.f);
    for (int l = l0; l < l1; ++l) {
        float4 xv = *(const float4*)(xb + (size_t)(l - l0) * Dd);
        float p1 = pos1[(size_t)b * Ls + l], p2 = pos2[(size_t)b * Ls + l];
        a1.x += xv.x * p1; a1.y += xv.y * p1; a1.z += xv.z * p1; a1.w += xv.w * p1;
        a2.x += xv.x * p2; a2.y += xv.y * p2; a2.z += xv.z * p2; a2.w += xv.w * p2;
    }
    float* e1 = eb + (size_t)b * Dd + d4;
    float* e2 = eb + (size_t)(Bb + b) * Dd + d4;
    atomicAdd(e1 + 0, a1.x); atomicAdd(e1 + 1, a1.y); atomicAdd(e1 + 2, a1.z); atomicAdd(e1 + 3, a1.w);
    atomicAdd(e2 + 0, a2.x); atomicAdd(e2 + 1, a2.y); atomicAdd(e2 + 2, a2.z); atomicAdd(e2 + 3, a2.w);
}

// ---- ge[b,j] += inv1*(e1raw·W1[:,j]) + inv2*(e2raw·W2[:,j]) (+fc1b once); grid (3,32,4)
__global__ void ge_kernel(const float* __restrict__ eb, const float* __restrict__ invb,
                          const float* __restrict__ fc1w, const float* __restrict__ fc1b,
                          float* __restrict__ geb) {
    __shared__ float es1[192], es2[192];
    int j = blockIdx.x * TB + threadIdx.x;
    int b = blockIdx.y, seg = blockIdx.z;
    if (threadIdx.x < 192) {
        es1[threadIdx.x] = eb[(size_t)b * Dd + seg * 192 + threadIdx.x];
        es2[threadIdx.x] = eb[(size_t)(Bb + b) * Dd + seg * 192 + threadIdx.x];
    }
    __syncthreads();
    float a1 = 0.f, a2 = 0.f;
    const float* w1 = fc1w + (size_t)(Dd + seg * 192) * Dd + j;
    const float* w2 = fc1w + (size_t)(2 * Dd + seg * 192) * Dd + j;
#pragma unroll 4
    for (int dd = 0; dd < 192; ++dd) {
        a1 += es1[dd] * w1[(size_t)dd * Dd];
        a2 += es2[dd] * w2[(size_t)dd * Dd];
    }
    float res = a1 * invb[b] + a2 * invb[32 + b] + (seg == 0 ? fc1b[j] : 0.f);
    atomicAdd(&geb[(size_t)b * Dd + j], res);
}

// ---- logits[r] = sigmoid( tanh(h[r,:]+ge[b,:]) · fc2w + fc2b ); 192 thr
__global__ void logits_row_kernel(const float* __restrict__ hb, const float* __restrict__ geb,
                                  const float* __restrict__ fc2w, const float* __restrict__ fc2b,
                                  float* __restrict__ out) {
    __shared__ float sh[3];
    int r = blockIdx.x, b = r / Cc;
    int d4 = threadIdx.x << 2;
    float4 h = *(const float4*)(hb + (size_t)r * Dd + d4);
    float4 ge4 = *(const float4*)(geb + (size_t)b * Dd + d4);
    float4 f = *(const float4*)(fc2w + d4);
    float t = tanhf(h.x + ge4.x) * f.x + tanhf(h.y + ge4.y) * f.y
            + tanhf(h.z + ge4.z) * f.z + tanhf(h.w + ge4.w) * f.w;
    t = blk_sum3(t, sh);
    if (threadIdx.x == 0) out[r] = 1.f / (1.f + expf(-(t + fc2b[0])));
}

// ---- pred[b] = argmax_c logits[b,c] (first max)
__global__ void argmax_kernel(const float* __restrict__ lg, float* __restrict__ pred) {
    int b = threadIdx.x;
    if (b < Bb) {
        const float* row = lg + (size_t)b * Cc;
        float best = row[0];
        int bi = 0;
        for (int c = 1; c < Cc; ++c) {
            float v = row[c];
            if (v > best) { best = v; bi = c; }
        }
        pred[b] = (float)bi;
    }
}

extern "C" void kernel_launch(void* const* d_in, const int* in_sizes, int n_in,
                              void* d_out, int out_size, void* d_ws, size_t ws_size,
                              hipStream_t stream) {
    const float* x0    = (const float*)d_in[0];
    const float* pos1  = (const float*)d_in[1];
    const float* pos2  = (const float*)d_in[2];
    const int*   mask  = (const int*)d_in[3];
    const float* emb   = (const float*)d_in[4];
    const float* rel_w = (const float*)d_in[5];
    const float* rel_b = (const float*)d_in[6];
    // qw,qb (7,8): dead — softmax is query-shift invariant
    const float* kw    = (const float*)d_in[9];
    // kb (10): dead — row-constant in score
    const float* vw    = (const float*)d_in[11];
    const float* vb    = (const float*)d_in[12];
    const float* sw    = (const float*)d_in[13];
    // sb (14): dead
    const float* gw    = (const float*)d_in[15];
    const float* gb    = (const float*)d_in[16];
    const float* fc1w  = (const float*)d_in[17];
    const float* fc1b  = (const float*)d_in[18];
    const float* fc2w  = (const float*)d_in[19];
    const float* fc2b  = (const float*)d_in[20];
    float* out = (float*)d_out;

    float* ws = (float*)d_ws;
    size_t off = 0;
    float* Pw    = ws + off; off += (size_t)Bb * Cc * Dd;
    float* Xw    = ws + off; off += (size_t)Bb * Ls * Dd;
    float* p0b   = ws + off; off += (size_t)Cc * Dd;
    float* kvecs = ws + off; off += (size_t)4 * Dd;
    float* ksb   = ws + off; off += (size_t)Bb * Ls;
    float* awb   = ws + off; off += (size_t)Bb * Ls;
    float* xab   = ws + off; off += (size_t)Bb * Dd;
    float* avb   = ws + off; off += (size_t)Bb * Dd;
    float* savb  = ws + off; off += 64;
    float* invb  = ws + off; off += 64;
    float* eb    = ws + off; off += (size_t)2 * Bb * Dd;
    float* geb   = ws + off; off += (size_t)Bb * Dd;
    float* hb    = ws + off; off += (size_t)Bb * Cc * Dd;

    // independent prep (also zeroes eb/geb for later atomics)
    pooldenom_kernel<<<Bb, TB, 0, stream>>>(pos1, pos2, invb, eb, geb);
    {
        dim3 g(Dd / 64, (Cc + 63) / 64);
        sgemm_kernel<<<g, TB, 0, stream>>>(emb, rel_w, rel_b, p0b, Cc, Dd, Dd);
    }
    kvec_kernel<<<dim3(Dd, 4), TB, 0, stream>>>(kw, sw, kvecs);
    // P broadcast + ks for li=0 RA1
    bcast_row_kernel<<<Bb * Cc, 192, 0, stream>>>(p0b, Pw, kvecs, ksb);

    const float* xsrc = x0;
    for (int li = 0; li < 2; ++li) {
        int i1 = li * 2 + 0, i2 = li * 2 + 1;
        const float* vw1 = vw + (size_t)i1 * Dd * Dd; const float* vb1 = vb + (size_t)i1 * Dd;
        const float* gw1 = gw + (size_t)i1 * 2 * Dd;  const float* gb1 = gb + i1;
        const float* vw2 = vw + (size_t)i2 * Dd * Dd; const float* vb2 = vb + (size_t)i2 * Dd;
        const float* gw2 = gw + (size_t)i2 * 2 * Dd;  const float* gb2 = gb + i2;

        // ---- RA1: update x; kv = P (N=C), no mask
        softmax_kernel<<<Bb, TB, 0, stream>>>(ksb, nullptr, awb, Cc, xab, avb);
        xa_kernel<<<dim3(Bb, 8), 192, 0, stream>>>(Pw, awb, xab, Cc, (Cc + 7) / 8);
        mm32_kernel<<<dim3(3, Bb, 4), TB, 0, stream>>>(xab, vw1, vb1, avb);
        rowdot_kernel<<<Bb, TB, 0, stream>>>(avb, gw1, savb);
        gate_kernel<<<Bb * Ls, 192, 0, stream>>>(xsrc, Xw, avb, savb, gw1, gb1,
                                                 kvecs + (size_t)i2 * Dd, ksb, Ls);
        xsrc = Xw;

        // ---- RA2: update p; kv = new x (N=L), masked
        softmax_kernel<<<Bb, TB, 0, stream>>>(ksb, mask, awb, Ls, xab, avb);
        xa_kernel<<<dim3(Bb, 8), 192, 0, stream>>>(Xw, awb, xab, Ls, Ls / 8);
        mm32_kernel<<<dim3(3, Bb, 4), TB, 0, stream>>>(xab, vw2, vb2, avb);
        rowdot_kernel<<<Bb, TB, 0, stream>>>(avb, gw2, savb);
        // fuse ks for next layer's RA1 (li=0 -> kvecs[2]); last layer: none
        const float* kn = (li == 0) ? kvecs + (size_t)2 * Dd : nullptr;
        float* ksn = (li == 0) ? ksb : nullptr;
        gate_kernel<<<Bb * Cc, 192, 0, stream>>>(Pw, Pw, avb, savb, gw2, gb2, kn, ksn, Cc);
    }

    // pooling + classifier
    poole_kernel<<<dim3(Bb, 8), 192, 0, stream>>>(Xw, pos1, pos2, eb, Ls / 8);
    ge_kernel<<<dim3(3, Bb, 4), TB, 0, stream>>>(eb, invb, fc1w, fc1b, geb);
    {
        dim3 g(Dd / 64, (Bb * Cc + 63) / 64);
        sgemm_kernel<<<g, TB, 0, stream>>>(Pw, fc1w, nullptr, hb, Bb * Cc, Dd, Dd);
    }
    logits_row_kernel<<<Bb * Cc, 192, 0, stream>>>(hb, geb, fc2w, fc2b, out);
    argmax_kernel<<<1, 64, 0, stream>>>(out, out + Bb * Cc);
}

// Round 3
// 484.678 us; speedup vs baseline: 2.0975x; 1.1583x over previous
//
#include <hip/hip_runtime.h>
#include <math.h>

static const int Bb = 32, Ls = 512, Dd = 768, Cc = 97;

// ---------- reductions ----------
__device__ __forceinline__ float blk_sum4(float v, float* sh) {
#pragma unroll
    for (int o = 32; o > 0; o >>= 1) v += __shfl_down(v, o, 64);
    int lane = threadIdx.x & 63, w = threadIdx.x >> 6;
    if (lane == 0) sh[w] = v;
    __syncthreads();
    float r = sh[0] + sh[1] + sh[2] + sh[3];
    __syncthreads();
    return r;
}
__device__ __forceinline__ float blk_sum3(float v, float* sh) {
#pragma unroll
    for (int o = 32; o > 0; o >>= 1) v += __shfl_down(v, o, 64);
    int lane = threadIdx.x & 63, w = threadIdx.x >> 6;
    if (lane == 0) sh[w] = v;
    __syncthreads();
    float r = sh[0] + sh[1] + sh[2];
    __syncthreads();
    return r;
}
__device__ __forceinline__ float4 blk_sum3_v4(float4 v, float* sh /*12*/) {
#pragma unroll
    for (int o = 32; o > 0; o >>= 1) {
        v.x += __shfl_down(v.x, o, 64); v.y += __shfl_down(v.y, o, 64);
        v.z += __shfl_down(v.z, o, 64); v.w += __shfl_down(v.w, o, 64);
    }
    int lane = threadIdx.x & 63, w = threadIdx.x >> 6;
    if (lane == 0) { sh[w*4+0]=v.x; sh[w*4+1]=v.y; sh[w*4+2]=v.z; sh[w*4+3]=v.w; }
    __syncthreads();
    float4 r;
    r.x = sh[0]+sh[4]+sh[8]; r.y = sh[1]+sh[5]+sh[9];
    r.z = sh[2]+sh[6]+sh[10]; r.w = sh[3]+sh[7]+sh[11];
    __syncthreads();
    return r;
}
__device__ __forceinline__ float sigm(float x) { return 1.f / (1.f + expf(-x)); }

// ---------- fp32 SGEMM: C[M,N] = A@W (+bias); N%64==0, K%16==0 ----------
__global__ __launch_bounds__(256) void sgemm_kernel(
        const float* __restrict__ A, const float* __restrict__ W,
        const float* __restrict__ bias, float* __restrict__ C,
        int M, int N, int K) {
    __shared__ float As[16][64];
    __shared__ float Ws[16][64];
    int tid = threadIdx.x;
    int tx = tid & 15, ty = tid >> 4;
    int bn = blockIdx.x * 64, bm = blockIdx.y * 64;
    int arow = tid >> 2, akq = (tid & 3) << 2;
    int wrow = tid >> 4, wcol = (tid & 15) << 2;
    int gar = bm + arow;
    bool aval = gar < M;
    const float* Ap = A + (size_t)gar * K + akq;
    const float* Wp = W + (size_t)wrow * N + bn + wcol;
    float acc[4][4] = {{0.f}};
    for (int k0 = 0; k0 < K; k0 += 16) {
        float4 a4 = make_float4(0.f,0.f,0.f,0.f);
        if (aval) a4 = *(const float4*)(Ap + k0);
        float4 w4 = *(const float4*)(Wp + (size_t)k0 * N);
        __syncthreads();
        As[akq+0][arow]=a4.x; As[akq+1][arow]=a4.y; As[akq+2][arow]=a4.z; As[akq+3][arow]=a4.w;
        *(float4*)&Ws[wrow][wcol] = w4;
        __syncthreads();
#pragma unroll
        for (int kk = 0; kk < 16; ++kk) {
            float4 a = *(const float4*)&As[kk][ty << 2];
            float4 b = *(const float4*)&Ws[kk][tx << 2];
            acc[0][0]+=a.x*b.x; acc[0][1]+=a.x*b.y; acc[0][2]+=a.x*b.z; acc[0][3]+=a.x*b.w;
            acc[1][0]+=a.y*b.x; acc[1][1]+=a.y*b.y; acc[1][2]+=a.y*b.z; acc[1][3]+=a.y*b.w;
            acc[2][0]+=a.z*b.x; acc[2][1]+=a.z*b.y; acc[2][2]+=a.z*b.z; acc[2][3]+=a.z*b.w;
            acc[3][0]+=a.w*b.x; acc[3][1]+=a.w*b.y; acc[3][2]+=a.w*b.z; acc[3][3]+=a.w*b.w;
        }
    }
    int gc = bn + (tx << 2);
    float4 bz = make_float4(0.f,0.f,0.f,0.f);
    if (bias) bz = *(const float4*)(bias + gc);
#pragma unroll
    for (int i = 0; i < 4; ++i) {
        int gr = bm + (ty << 2) + i;
        if (gr < M) {
            float4 r;
            r.x=acc[i][0]+bz.x; r.y=acc[i][1]+bz.y; r.z=acc[i][2]+bz.z; r.w=acc[i][3]+bz.w;
            *(float4*)(C + (size_t)gr * N + gc) = r;
        }
    }
}

// ---------- kvec[i][d] = kw[i][d][:] . sw[i][D:2D] ----------
__global__ void kvec_kernel(const float* __restrict__ kw, const float* __restrict__ sw,
                            float* __restrict__ kvecs) {
    __shared__ float sh[4];
    int idx = blockIdx.y, d = blockIdx.x;
    const float* row = kw + ((size_t)idx * Dd + d) * Dd;
    const float* swk = sw + (size_t)idx * 2 * Dd + Dd;
    float t = 0.f;
    for (int j = threadIdx.x; j < Dd; j += 256) t += row[j] * swk[j];
    t = blk_sum4(t, sh);
    if (threadIdx.x == 0) kvecs[(size_t)idx * Dd + d] = t;
}

// ---------- generic row-dots: out[v*stride + r] = A[r,:]·(vXa (+ vXb)) ----------
__global__ void rowdots_kernel(const float* __restrict__ A,
        const float* v0a, const float* v0b, const float* v1a, const float* v1b,
        const float* v2a, const float* v2b, const float* v3a, const float* v3b,
        float* __restrict__ out, int outstride) {
    __shared__ float sh[4];
    int r = blockIdx.x, v = blockIdx.y;
    const float *va, *vbp;
    switch (v) {
        case 0: va = v0a; vbp = v0b; break;
        case 1: va = v1a; vbp = v1b; break;
        case 2: va = v2a; vbp = v2b; break;
        default: va = v3a; vbp = v3b; break;
    }
    const float* row = A + (size_t)r * Dd;
    float t = 0.f;
    for (int j = threadIdx.x; j < Dd; j += 256) {
        float wv = va[j] + (vbp ? vbp[j] : 0.f);
        t += row[j] * wv;
    }
    t = blk_sum4(t, sh);
    if (threadIdx.x == 0) out[(size_t)v * outstride + r] = t;
}

// ---------- pass A: 4 fused row-dots of x0 (one 50MB read), 192 thr/row ----------
// xd[r*4+..] = { x0·gwsum0, x0·kvec1, x0·gwsum2, x0·kvec3 }
__global__ void xdots_kernel(const float* __restrict__ x0, const float* __restrict__ kvecs,
                             const float* __restrict__ gw, float* __restrict__ xd) {
    __shared__ float sh[12];
    int r = blockIdx.x;
    int d4 = threadIdx.x << 2;
    float4 x = *(const float4*)(x0 + (size_t)r * Dd + d4);
    float4 g0a = *(const float4*)(gw + d4);
    float4 g0b = *(const float4*)(gw + Dd + d4);
    float4 g2a = *(const float4*)(gw + 2 * 1536 + d4);
    float4 g2b = *(const float4*)(gw + 2 * 1536 + Dd + d4);
    float4 k1 = *(const float4*)(kvecs + Dd + d4);
    float4 k3 = *(const float4*)(kvecs + 3 * Dd + d4);
    float4 p;
    p.x = x.x*(g0a.x+g0b.x) + x.y*(g0a.y+g0b.y) + x.z*(g0a.z+g0b.z) + x.w*(g0a.w+g0b.w);
    p.y = x.x*k1.x + x.y*k1.y + x.z*k1.z + x.w*k1.w;
    p.z = x.x*(g2a.x+g2b.x) + x.y*(g2a.y+g2b.y) + x.z*(g2a.z+g2b.z) + x.w*(g2a.w+g2b.w);
    p.w = x.x*k3.x + x.y*k3.y + x.z*k3.z + x.w*k3.w;
    p = blk_sum3_v4(p, sh);
    if (threadIdx.x == 0) *(float4*)(xd + (size_t)r * 4) = p;
}

// ---------- attention over P (N=C=97) + weighted-sum combine; 192 thr, block=b ----------
// w = softmax_c(ks);  xaP[b,:] = alpha*sum_c w*p0[c,:] + (g1? (sum_c w*g1)*av1[b,:] : 0)
// also zeroes zeroT[b,:] (next mm32 atomic target)
__global__ void attnP_kernel(const float* __restrict__ ksP, const float* __restrict__ pdk,
                             const float* __restrict__ p0, const float* __restrict__ g1,
                             const float* __restrict__ av1, float alpha,
                             float* __restrict__ xaP, float* __restrict__ zeroT) {
    __shared__ float lw[97];
    __shared__ float sh[12];
    int b = blockIdx.x, t = threadIdx.x;
    float v = -3.0e38f;
    if (t < Cc) v = ksP ? ksP[(size_t)b * Cc + t] : pdk[t];
    // max over 97 (3-wave max reduce)
    float m = v;
#pragma unroll
    for (int o = 32; o > 0; o >>= 1) m = fmaxf(m, __shfl_down(m, o, 64));
    int lane = t & 63, wv = t >> 6;
    if (lane == 0) sh[wv] = m;
    __syncthreads();
    m = fmaxf(fmaxf(sh[0], sh[1]), sh[2]);
    __syncthreads();
    float e = (t < Cc) ? expf(v - m) : 0.f;
    float s = blk_sum3(e, sh);
    float wc = e / s;
    if (t < Cc) lw[t] = wc;
    float cg = 0.f;
    if (g1) {
        float gv = (t < Cc) ? wc * g1[(size_t)b * Cc + t] : 0.f;
        cg = blk_sum3(gv, sh);
    }
    __syncthreads();
    int d4 = t << 2;
    // zero the upcoming atomic target row
    *(float4*)(zeroT + (size_t)b * Dd + d4) = make_float4(0.f,0.f,0.f,0.f);
    float4 acc = make_float4(0.f,0.f,0.f,0.f);
    for (int c = 0; c < Cc; ++c) {
        float w = lw[c];
        float4 pv = *(const float4*)(p0 + (size_t)c * Dd + d4);
        acc.x += w*pv.x; acc.y += w*pv.y; acc.z += w*pv.z; acc.w += w*pv.w;
    }
    float4 o;
    o.x = alpha*acc.x; o.y = alpha*acc.y; o.z = alpha*acc.z; o.w = alpha*acc.w;
    if (g1) {
        float4 a = *(const float4*)(av1 + (size_t)b * Dd + d4);
        o.x += cg*a.x; o.y += cg*a.y; o.z += cg*a.z; o.w += cg*a.w;
    }
    *(float4*)(xaP + (size_t)b * Dd + d4) = o;
}

// ---------- small GEMV bank: out[b,j] += xs·W[:,j]; xs = gamma*S + multA*coefA[b]*avA + multB*coefB[b]*avB
// grid (3, nrows, 4), 256 thr
__global__ void mm32_kernel(const float* __restrict__ S, float gamma,
                            const float* __restrict__ avA, const float* __restrict__ coefA, float multA,
                            const float* __restrict__ avB, const float* __restrict__ coefB, float multB,
                            const float* __restrict__ W, const float* __restrict__ bias,
                            float* __restrict__ out) {
    __shared__ float xs[192];
    int t = threadIdx.x;
    int b = blockIdx.y, seg = blockIdx.z;
    if (t < 192) {
        int d = seg * 192 + t;
        float v = gamma * S[(size_t)b * Dd + d];
        if (avA) v += multA * coefA[b] * avA[(size_t)b * Dd + d];
        if (avB) v += multB * coefB[b] * avB[(size_t)b * Dd + d];
        xs[t] = v;
    }
    __syncthreads();
    int j = blockIdx.x * 256 + t;
    float acc = (seg == 0 && bias) ? bias[j] : 0.f;
    const float* wp = W + (size_t)(seg * 192) * Dd + j;
#pragma unroll 4
    for (int dd = 0; dd < 192; ++dd) acc += xs[dd] * wp[(size_t)dd * Dd];
    atomicAdd(&out[(size_t)b * Dd + j], acc);
}

// ---------- X-gate coefficient kernels (elementwise over B*L) ----------
__global__ void xgate_kernel(const float* __restrict__ xd, const float* __restrict__ sc,
                             const float* __restrict__ gb, float* __restrict__ gx1,
                             float* __restrict__ gx2, float* __restrict__ ks2, int phase) {
    int r = blockIdx.x * 256 + threadIdx.x;   // exactly B*L = 16384
    int b = r >> 9;
    float4 x = *(const float4*)(xd + (size_t)r * 4);
    if (phase == 0) {
        float g = sigm(x.x + sc[0 + b] + gb[0]);
        gx1[r] = g;
        ks2[r] = 2.f * x.y + g * sc[32 + b];
    } else {
        float gp = gx1[r];
        float g = sigm(2.f * x.z + gp * sc[64 + b] + sc[224 + b] + gb[2]);
        gx2[r] = g;
        ks2[r] = 4.f * x.w + 2.f * gp * sc[96 + b] + g * sc[256 + b];
    }
}

// ---------- P-gate layer0: g1, ksP1 over B*C ----------
__global__ void pgate_kernel(const float* __restrict__ pdots, const float* __restrict__ sc,
                             const float* __restrict__ gb, float* __restrict__ g1buf,
                             float* __restrict__ ksP1) {
    int r = blockIdx.x * 256 + threadIdx.x;
    if (r >= Bb * Cc) return;
    int b = r / Cc, c = r - b * Cc;
    float g = sigm(pdots[194 + c] + sc[128 + b] + gb[1]);
    g1buf[r] = g;
    ksP1[r] = 2.f * pdots[97 + c] + g * sc[160 + b];
}

// ---------- masked softmax over L=512 + up to 2 coef sums + zero up to 4 rows ----------
__global__ void softmaxX_kernel(const float* __restrict__ ks, const int* __restrict__ mask,
                                float* __restrict__ w,
                                const float* __restrict__ gxa, const float* __restrict__ gxb,
                                float* __restrict__ cwout,
                                float* z0, float* z1, float* z2, float* z3) {
    __shared__ float sh[4];
    int b = blockIdx.x, t = threadIdx.x;
    const float* row = ks + (size_t)b * Ls;
    const int* mrow = mask + (size_t)b * Ls;
    float v0 = row[t],       v1 = row[t + 256];
    if (mrow[t] == 0) v0 = -1e9f;
    if (mrow[t + 256] == 0) v1 = -1e9f;
    float mx = fmaxf(v0, v1);
#pragma unroll
    for (int o = 32; o > 0; o >>= 1) mx = fmaxf(mx, __shfl_down(mx, o, 64));
    if ((t & 63) == 0) sh[t >> 6] = mx;
    __syncthreads();
    mx = fmaxf(fmaxf(sh[0], sh[1]), fmaxf(sh[2], sh[3]));
    __syncthreads();
    float e0 = expf(v0 - mx), e1 = expf(v1 - mx);
    float s = blk_sum4(e0 + e1, sh);
    float inv = 1.f / s;
    float w0 = e0 * inv, w1 = e1 * inv;
    w[(size_t)b * Ls + t] = w0;
    w[(size_t)b * Ls + t + 256] = w1;
    if (gxa) {
        float ca = w0 * gxa[(size_t)b * Ls + t] + w1 * gxa[(size_t)b * Ls + t + 256];
        ca = blk_sum4(ca, sh);
        if (t == 0) cwout[b] = ca;
    }
    if (gxb) {
        float cb = w0 * gxb[(size_t)b * Ls + t] + w1 * gxb[(size_t)b * Ls + t + 256];
        cb = blk_sum4(cb, sh);
        if (t == 0) cwout[32 + b] = cb;
    }
    // zero atomic targets (768 floats per listed row)
    for (int d = t; d < Dd; d += 256) {
        if (z0) z0[(size_t)b * Dd + d] = 0.f;
        if (z1) z1[(size_t)b * Dd + d] = 0.f;
        if (z2) z2[(size_t)b * Dd + d] = 0.f;
        if (z3) z3[(size_t)b * Dd + d] = 0.f;
    }
}

// ---------- big pass over x0: S += sum_l w*x0 (+ optional pos1/pos2 sums) ----------
__global__ void passX_kernel(const float* __restrict__ x0, const float* __restrict__ w,
                             const float* __restrict__ pos1, const float* __restrict__ pos2,
                             float* __restrict__ S, float* __restrict__ xp1, float* __restrict__ xp2) {
    int b = blockIdx.x, seg = blockIdx.y;
    int l0 = seg * 64;
    int d4 = threadIdx.x << 2;
    const float* xb = x0 + ((size_t)b * Ls + l0) * Dd + d4;
    float4 as = make_float4(0.f,0.f,0.f,0.f);
    float4 a1 = make_float4(0.f,0.f,0.f,0.f);
    float4 a2 = make_float4(0.f,0.f,0.f,0.f);
    for (int l = 0; l < 64; ++l) {
        float4 xv = *(const float4*)(xb + (size_t)l * Dd);
        float wv = w[(size_t)b * Ls + l0 + l];
        as.x += wv*xv.x; as.y += wv*xv.y; as.z += wv*xv.z; as.w += wv*xv.w;
        if (pos1) {
            float p1 = pos1[(size_t)b * Ls + l0 + l], p2 = pos2[(size_t)b * Ls + l0 + l];
            a1.x += p1*xv.x; a1.y += p1*xv.y; a1.z += p1*xv.z; a1.w += p1*xv.w;
            a2.x += p2*xv.x; a2.y += p2*xv.y; a2.z += p2*xv.z; a2.w += p2*xv.w;
        }
    }
    float* ds = S + (size_t)b * Dd + d4;
    atomicAdd(ds+0, as.x); atomicAdd(ds+1, as.y); atomicAdd(ds+2, as.z); atomicAdd(ds+3, as.w);
    if (pos1) {
        float* d1 = xp1 + (size_t)b * Dd + d4;
        float* d2 = xp2 + (size_t)b * Dd + d4;
        atomicAdd(d1+0, a1.x); atomicAdd(d1+1, a1.y); atomicAdd(d1+2, a1.z); atomicAdd(d1+3, a1.w);
        atomicAdd(d2+0, a2.x); atomicAdd(d2+1, a2.y); atomicAdd(d2+2, a2.z); atomicAdd(d2+3, a2.w);
    }
}

// ---------- pool coefficients + denominators; zero aw12 rows ----------
__global__ void poolcoef_kernel(const float* __restrict__ pos1, const float* __restrict__ pos2,
                                const float* __restrict__ gx1, const float* __restrict__ gx2,
                                float* __restrict__ sc, float* __restrict__ aw12) {
    __shared__ float sh[4];
    int b = blockIdx.x, t = threadIdx.x;
    float p1a = pos1[(size_t)b*Ls + t], p1b = pos1[(size_t)b*Ls + t + 256];
    float p2a = pos2[(size_t)b*Ls + t], p2b = pos2[(size_t)b*Ls + t + 256];
    float g1a = gx1[(size_t)b*Ls + t], g1b = gx1[(size_t)b*Ls + t + 256];
    float g2a = gx2[(size_t)b*Ls + t], g2b = gx2[(size_t)b*Ls + t + 256];
    float s1 = blk_sum4(p1a + p1b, sh);
    float s2 = blk_sum4(p2a + p2b, sh);
    float c11 = blk_sum4(p1a*g1a + p1b*g1b, sh);
    float c12 = blk_sum4(p1a*g2a + p1b*g2b, sh);
    float c21 = blk_sum4(p2a*g1a + p2b*g1b, sh);
    float c22 = blk_sum4(p2a*g2a + p2b*g2b, sh);
    if (t == 0) {
        sc[448+b] = c11; sc[480+b] = c12; sc[512+b] = c21; sc[544+b] = c22;
        sc[576+b] = 1.f / s1; sc[608+b] = 1.f / s2;
    }
    for (int d = t; d < Dd; d += 256) {
        aw12[(size_t)b * Dd + d] = 0.f;
        aw12[(size_t)(32 + b) * Dd + d] = 0.f;
    }
}

// ---------- ge[b,j] = e1·W1 + e2·W2 + fc1b (e built in-kernel); grid (3,32,4) ----------
__global__ void ge_kernel(const float* __restrict__ xp1, const float* __restrict__ xp2,
                          const float* __restrict__ avx1, const float* __restrict__ avx2,
                          const float* __restrict__ sc, const float* __restrict__ fc1w,
                          const float* __restrict__ fc1b, float* __restrict__ geb) {
    __shared__ float es1[192], es2[192];
    int t = threadIdx.x;
    int b = blockIdx.y, seg = blockIdx.z;
    if (t < 192) {
        int d = seg * 192 + t;
        float a1 = avx1[(size_t)b * Dd + d], a2 = avx2[(size_t)b * Dd + d];
        es1[t] = (4.f * xp1[(size_t)b * Dd + d] + 2.f * sc[448+b] * a1 + sc[480+b] * a2) * sc[576+b];
        es2[t] = (4.f * xp2[(size_t)b * Dd + d] + 2.f * sc[512+b] * a1 + sc[544+b] * a2) * sc[608+b];
    }
    __syncthreads();
    int j = blockIdx.x * 256 + t;
    float a1 = 0.f, a2 = 0.f;
    const float* w1 = fc1w + (size_t)(Dd + seg * 192) * Dd + j;
    const float* w2 = fc1w + (size_t)(2 * Dd + seg * 192) * Dd + j;
#pragma unroll 4
    for (int dd = 0; dd < 192; ++dd) {
        a1 += es1[dd] * w1[(size_t)dd * Dd];
        a2 += es2[dd] * w2[(size_t)dd * Dd];
    }
    float res = a1 + a2 + (seg == 0 ? fc1b[j] : 0.f);
    atomicAdd(&geb[(size_t)b * Dd + j], res);
}

// ---------- logits: h=tanh(4pp + 2g1 aw1 + g2 aw2 + ge); out=sigm(h·fc2w+fc2b) ----------
__global__ void logits_kernel(const float* __restrict__ g1buf, const float* __restrict__ pdots,
                              const float* __restrict__ sc, const float* __restrict__ gb,
                              const float* __restrict__ pp, const float* __restrict__ aw12,
                              const float* __restrict__ geb, const float* __restrict__ fc2w,
                              const float* __restrict__ fc2b, float* __restrict__ out) {
    __shared__ float sh[3];
    int r = blockIdx.x;
    int b = r / Cc, c = r - b * Cc;
    float g1 = g1buf[r];
    float g2 = sigm(2.f * pdots[291 + c] + g1 * sc[192 + b] + sc[288 + b] + gb[3]);
    int d4 = threadIdx.x << 2;
    float4 ppv = *(const float4*)(pp + (size_t)c * Dd + d4);
    float4 a1v = *(const float4*)(aw12 + (size_t)b * Dd + d4);
    float4 a2v = *(const float4*)(aw12 + (size_t)(32 + b) * Dd + d4);
    float4 gev = *(const float4*)(geb + (size_t)b * Dd + d4);
    float4 fv  = *(const float4*)(fc2w + d4);
    float t = tanhf(4.f*ppv.x + 2.f*g1*a1v.x + g2*a2v.x + gev.x) * fv.x
            + tanhf(4.f*ppv.y + 2.f*g1*a1v.y + g2*a2v.y + gev.y) * fv.y
            + tanhf(4.f*ppv.z + 2.f*g1*a1v.z + g2*a2v.z + gev.z) * fv.z
            + tanhf(4.f*ppv.w + 2.f*g1*a1v.w + g2*a2v.w + gev.w) * fv.w;
    t = blk_sum3(t, sh);
    if (threadIdx.x == 0) out[r] = sigm(t + fc2b[0]);
}

__global__ void argmax_kernel(const float* __restrict__ lg, float* __restrict__ pred) {
    int b = threadIdx.x;
    if (b < Bb) {
        const float* row = lg + (size_t)b * Cc;
        float best = row[0];
        int bi = 0;
        for (int c = 1; c < Cc; ++c) {
            float v = row[c];
            if (v > best) { best = v; bi = c; }
        }
        pred[b] = (float)bi;
    }
}

extern "C" void kernel_launch(void* const* d_in, const int* in_sizes, int n_in,
                              void* d_out, int out_size, void* d_ws, size_t ws_size,
                              hipStream_t stream) {
    const float* x0    = (const float*)d_in[0];
    const float* pos1  = (const float*)d_in[1];
    const float* pos2  = (const float*)d_in[2];
    const int*   mask  = (const int*)d_in[3];
    const float* emb   = (const float*)d_in[4];
    const float* rel_w = (const float*)d_in[5];
    const float* rel_b = (const float*)d_in[6];
    // qw(7), qb(8): dead — softmax shift-invariance kills the query branch
    const float* kw    = (const float*)d_in[9];
    // kb(10), sb(14): dead — row-constant in the softmax
    const float* vw    = (const float*)d_in[11];
    const float* vb    = (const float*)d_in[12];
    const float* sw    = (const float*)d_in[13];
    const float* gw    = (const float*)d_in[15];
    const float* gb    = (const float*)d_in[16];
    const float* fc1w  = (const float*)d_in[17];
    const float* fc1b  = (const float*)d_in[18];
    const float* fc2w  = (const float*)d_in[19];
    const float* fc2b  = (const float*)d_in[20];
    float* out = (float*)d_out;

    // gw slices
    const float* gw0a = gw;            const float* gw0b = gw + Dd;
    const float* gw1a = gw + 1536;     const float* gw1b = gw + 1536 + Dd;
    const float* gw2a = gw + 3072;     const float* gw2b = gw + 3072 + Dd;
    const float* gw3a = gw + 4608;     const float* gw3b = gw + 4608 + Dd;

    float* ws = (float*)d_ws;
    size_t off = 0;
    float* p0b   = ws + off; off += (size_t)Cc * Dd;      // 97x768
    float* pp    = ws + off; off += (size_t)Cc * Dd;      // p0@fc1w0
    float* kvecs = ws + off; off += (size_t)4 * Dd;
    float* pdots = ws + off; off += 388;                  // 4x97: k0,k2,g1,g3
    float* xd    = ws + off; off += (size_t)Bb * Ls * 4;  // 4 x0-dots per row
    float* gx1   = ws + off; off += (size_t)Bb * Ls;
    float* gx2   = ws + off; off += (size_t)Bb * Ls;
    float* ks2   = ws + off; off += (size_t)Bb * Ls;
    float* awb   = ws + off; off += (size_t)Bb * Ls;
    float* ksP1  = ws + off; off += (size_t)Bb * Cc;      // 3104
    float* g1buf = ws + off; off += (size_t)Bb * Cc;
    float* xaPb  = ws + off; off += (size_t)Bb * Dd;
    float* avx1  = ws + off; off += (size_t)Bb * Dd;
    float* avx2  = ws + off; off += (size_t)Bb * Dd;
    float* av12  = ws + off; off += (size_t)2 * Bb * Dd;  // av1|av2 contiguous
    float* aw12  = ws + off; off += (size_t)2 * Bb * Dd;  // aw1|aw2
    float* S0    = ws + off; off += (size_t)Bb * Dd;
    float* xp1   = ws + off; off += (size_t)Bb * Dd;
    float* xp2   = ws + off; off += (size_t)Bb * Dd;
    float* geb   = ws + off; off += (size_t)Bb * Dd;
    float* sc    = ws + off; off += 640;
    float* av1 = av12;
    float* av2 = av12 + (size_t)Bb * Dd;

    // ---- prep
    kvec_kernel<<<dim3(Dd, 4), 256, 0, stream>>>(kw, sw, kvecs);
    sgemm_kernel<<<dim3(12, 2), 256, 0, stream>>>(emb, rel_w, rel_b, p0b, Cc, Dd, Dd);
    sgemm_kernel<<<dim3(12, 2), 256, 0, stream>>>(p0b, fc1w, nullptr, pp, Cc, Dd, Dd);
    rowdots_kernel<<<dim3(Cc, 4), 256, 0, stream>>>(p0b,
        kvecs, nullptr, kvecs + 2*Dd, nullptr, gw1a, gw1b, gw3a, gw3b, pdots, Cc);
    xdots_kernel<<<Bb * Ls, 192, 0, stream>>>(x0, kvecs, gw, xd);

    // ---- layer 0, RA1 (x-side av)
    attnP_kernel<<<Bb, 192, 0, stream>>>(nullptr, pdots, p0b, nullptr, nullptr, 1.f, xaPb, avx1);
    mm32_kernel<<<dim3(3, Bb, 4), 256, 0, stream>>>(xaPb, 1.f, nullptr, nullptr, 0.f,
        nullptr, nullptr, 0.f, vw, vb, avx1);
    rowdots_kernel<<<dim3(Bb, 4), 256, 0, stream>>>(avx1,
        gw0a, nullptr, kvecs + Dd, nullptr, gw2a, gw2b, kvecs + 3*Dd, nullptr, sc, 32);
    xgate_kernel<<<64, 256, 0, stream>>>(xd, sc, gb, gx1, gx2, ks2, 0);

    // ---- layer 0, RA2 (p-side av)
    softmaxX_kernel<<<Bb, 256, 0, stream>>>(ks2, mask, awb, gx1, nullptr, sc + 320,
        S0, xp1, xp2, av1);
    passX_kernel<<<dim3(Bb, 8), 192, 0, stream>>>(x0, awb, pos1, pos2, S0, xp1, xp2);
    mm32_kernel<<<dim3(3, Bb, 4), 256, 0, stream>>>(S0, 2.f, avx1, sc + 320, 1.f,
        nullptr, nullptr, 0.f, vw + (size_t)1*Dd*Dd, vb + Dd, av1);
    rowdots_kernel<<<dim3(Bb, 3), 256, 0, stream>>>(av1,
        gw1a, nullptr, kvecs + 2*Dd, nullptr, gw3a, gw3b, nullptr, nullptr, sc + 128, 32);
    pgate_kernel<<<13, 256, 0, stream>>>(pdots, sc, gb, g1buf, ksP1);

    // ---- layer 1, RA1
    attnP_kernel<<<Bb, 192, 0, stream>>>(ksP1, nullptr, p0b, g1buf, av1, 2.f, xaPb, avx2);
    mm32_kernel<<<dim3(3, Bb, 4), 256, 0, stream>>>(xaPb, 1.f, nullptr, nullptr, 0.f,
        nullptr, nullptr, 0.f, vw + (size_t)2*Dd*Dd, vb + 2*Dd, avx2);
    rowdots_kernel<<<dim3(Bb, 2), 256, 0, stream>>>(avx2,
        gw2a, nullptr, kvecs + 3*Dd, nullptr, nullptr, nullptr, nullptr, nullptr, sc + 224, 32);
    xgate_kernel<<<64, 256, 0, stream>>>(xd, sc, gb, gx1, gx2, ks2, 1);

    // ---- layer 1, RA2
    softmaxX_kernel<<<Bb, 256, 0, stream>>>(ks2, mask, awb, gx1, gx2, sc + 352,
        S0, av2, geb, nullptr);
    passX_kernel<<<dim3(Bb, 8), 192, 0, stream>>>(x0, awb, nullptr, nullptr, S0, nullptr, nullptr);
    mm32_kernel<<<dim3(3, Bb, 4), 256, 0, stream>>>(S0, 4.f, avx1, sc + 352, 2.f,
        avx2, sc + 384, 1.f, vw + (size_t)3*Dd*Dd, vb + 3*Dd, av2);
    rowdots_kernel<<<dim3(Bb, 1), 256, 0, stream>>>(av2,
        gw3a, nullptr, nullptr, nullptr, nullptr, nullptr, nullptr, nullptr, sc + 288, 32);

    // ---- classifier head
    poolcoef_kernel<<<Bb, 256, 0, stream>>>(pos1, pos2, gx1, gx2, sc, aw12);
    ge_kernel<<<dim3(3, Bb, 4), 256, 0, stream>>>(xp1, xp2, avx1, avx2, sc, fc1w, fc1b, geb);
    mm32_kernel<<<dim3(3, 2 * Bb, 4), 256, 0, stream>>>(av12, 1.f, nullptr, nullptr, 0.f,
        nullptr, nullptr, 0.f, fc1w, nullptr, aw12);
    logits_kernel<<<Bb * Cc, 192, 0, stream>>>(g1buf, pdots, sc, gb, pp, aw12, geb,
        fc2w, fc2b, out);
    argmax_kernel<<<1, 64, 0, stream>>>(out, out + Bb * Cc);
}

// Round 4
// 409.670 us; speedup vs baseline: 2.4815x; 1.1831x over previous
//
#include <hip/hip_runtime.h>
#include <math.h>

static const int Bb = 32, Ls = 512, Dd = 768, Cc = 97;

// ---------- reductions ----------
__device__ __forceinline__ float blk_sum4(float v, float* sh) {
#pragma unroll
    for (int o = 32; o > 0; o >>= 1) v += __shfl_down(v, o, 64);
    int lane = threadIdx.x & 63, w = threadIdx.x >> 6;
    if (lane == 0) sh[w] = v;
    __syncthreads();
    float r = sh[0] + sh[1] + sh[2] + sh[3];
    __syncthreads();
    return r;
}
__device__ __forceinline__ float blk_sum3(float v, float* sh) {
#pragma unroll
    for (int o = 32; o > 0; o >>= 1) v += __shfl_down(v, o, 64);
    int lane = threadIdx.x & 63, w = threadIdx.x >> 6;
    if (lane == 0) sh[w] = v;
    __syncthreads();
    float r = sh[0] + sh[1] + sh[2];
    __syncthreads();
    return r;
}
__device__ __forceinline__ float4 blk_sum3_v4(float4 v, float* sh /*12*/) {
#pragma unroll
    for (int o = 32; o > 0; o >>= 1) {
        v.x += __shfl_down(v.x, o, 64); v.y += __shfl_down(v.y, o, 64);
        v.z += __shfl_down(v.z, o, 64); v.w += __shfl_down(v.w, o, 64);
    }
    int lane = threadIdx.x & 63, w = threadIdx.x >> 6;
    if (lane == 0) { sh[w*4+0]=v.x; sh[w*4+1]=v.y; sh[w*4+2]=v.z; sh[w*4+3]=v.w; }
    __syncthreads();
    float4 r;
    r.x = sh[0]+sh[4]+sh[8]; r.y = sh[1]+sh[5]+sh[9];
    r.z = sh[2]+sh[6]+sh[10]; r.w = sh[3]+sh[7]+sh[11];
    __syncthreads();
    return r;
}
__device__ __forceinline__ float sigm(float x) { return 1.f / (1.f + expf(-x)); }

// ---------- split-K SGEMM: C[M,N] += A@W chunk (+bias from z==0); C pre-zeroed ----------
__global__ __launch_bounds__(256) void sgemm_splitk_kernel(
        const float* __restrict__ A, const float* __restrict__ W,
        const float* __restrict__ bias, float* __restrict__ C,
        int M, int N, int K, int KC) {
    __shared__ float As[16][64];
    __shared__ float Ws[16][64];
    int tid = threadIdx.x;
    int tx = tid & 15, ty = tid >> 4;
    int bn = blockIdx.x * 64, bm = blockIdx.y * 64;
    int kb = blockIdx.z * KC;
    int arow = tid >> 2, akq = (tid & 3) << 2;
    int wrow = tid >> 4, wcol = (tid & 15) << 2;
    int gar = bm + arow;
    bool aval = gar < M;
    const float* Ap = A + (size_t)gar * K + kb + akq;
    const float* Wp = W + (size_t)(kb + wrow) * N + bn + wcol;
    float acc[4][4] = {{0.f}};
    float4 a4 = make_float4(0.f,0.f,0.f,0.f);
    if (aval) a4 = *(const float4*)Ap;
    float4 w4 = *(const float4*)Wp;
    for (int k0 = 0; k0 < KC; k0 += 16) {
        __syncthreads();
        As[akq+0][arow]=a4.x; As[akq+1][arow]=a4.y; As[akq+2][arow]=a4.z; As[akq+3][arow]=a4.w;
        *(float4*)&Ws[wrow][wcol] = w4;
        __syncthreads();
        if (k0 + 16 < KC) {           // prefetch next tile while computing
            if (aval) a4 = *(const float4*)(Ap + k0 + 16);
            w4 = *(const float4*)(Wp + (size_t)(k0 + 16) * N);
        }
#pragma unroll
        for (int kk = 0; kk < 16; ++kk) {
            float4 a = *(const float4*)&As[kk][ty << 2];
            float4 b = *(const float4*)&Ws[kk][tx << 2];
            acc[0][0]+=a.x*b.x; acc[0][1]+=a.x*b.y; acc[0][2]+=a.x*b.z; acc[0][3]+=a.x*b.w;
            acc[1][0]+=a.y*b.x; acc[1][1]+=a.y*b.y; acc[1][2]+=a.y*b.z; acc[1][3]+=a.y*b.w;
            acc[2][0]+=a.z*b.x; acc[2][1]+=a.z*b.y; acc[2][2]+=a.z*b.z; acc[2][3]+=a.z*b.w;
            acc[3][0]+=a.w*b.x; acc[3][1]+=a.w*b.y; acc[3][2]+=a.w*b.z; acc[3][3]+=a.w*b.w;
        }
    }
    int gc = bn + (tx << 2);
    float4 bz = make_float4(0.f,0.f,0.f,0.f);
    if (blockIdx.z == 0 && bias) bz = *(const float4*)(bias + gc);
#pragma unroll
    for (int i = 0; i < 4; ++i) {
        int gr = bm + (ty << 2) + i;
        if (gr < M) {
            float* cp = C + (size_t)gr * N + gc;
            atomicAdd(cp+0, acc[i][0]+bz.x); atomicAdd(cp+1, acc[i][1]+bz.y);
            atomicAdd(cp+2, acc[i][2]+bz.z); atomicAdd(cp+3, acc[i][3]+bz.w);
        }
    }
}

// ---------- kvec[i][d] = kw[i][d][:]·sw[i][D:2D]; also zeroes [p0b|pp|sc] region ----------
__global__ void kvec_kernel(const float* __restrict__ kw, const float* __restrict__ sw,
                            float* __restrict__ kvecs, float* __restrict__ zbuf, int zn) {
    __shared__ float sh[4];
    int idx = blockIdx.y, d = blockIdx.x;
    int g = idx * Dd + d;                 // 0..3071
    int zi = g * 49 + threadIdx.x;
    if (threadIdx.x < 49 && zi < zn) zbuf[zi] = 0.f;
    const float* row = kw + ((size_t)idx * Dd + d) * Dd;
    const float* swk = sw + (size_t)idx * 2 * Dd + Dd;
    float t = 0.f;
    for (int j = threadIdx.x; j < Dd; j += 256) t += row[j] * swk[j];
    t = blk_sum4(t, sh);
    if (threadIdx.x == 0) kvecs[(size_t)idx * Dd + d] = t;
}

// ---------- pdots: out[v*97 + r] = p0[r,:]·(vXa (+vXb)) ----------
__global__ void rowdots_kernel(const float* __restrict__ A,
        const float* v0a, const float* v0b, const float* v1a, const float* v1b,
        const float* v2a, const float* v2b, const float* v3a, const float* v3b,
        float* __restrict__ out, int outstride) {
    __shared__ float sh[4];
    int r = blockIdx.x, v = blockIdx.y;
    const float *va, *vbp;
    switch (v) {
        case 0: va = v0a; vbp = v0b; break;
        case 1: va = v1a; vbp = v1b; break;
        case 2: va = v2a; vbp = v2b; break;
        default: va = v3a; vbp = v3b; break;
    }
    const float* row = A + (size_t)r * Dd;
    float t = 0.f;
    for (int j = threadIdx.x; j < Dd; j += 256) {
        float wv = va[j] + (vbp ? vbp[j] : 0.f);
        t += row[j] * wv;
    }
    t = blk_sum4(t, sh);
    if (threadIdx.x == 0) out[(size_t)v * outstride + r] = t;
}

// ---------- xdots: 4 fused x0 row-dots, 8 rows/block with prefetch; 192 thr ----------
__global__ void xdots_kernel(const float* __restrict__ x0, const float* __restrict__ kvecs,
                             const float* __restrict__ gw, float* __restrict__ xd) {
    __shared__ float sh[12];
    size_t r0 = (size_t)blockIdx.x * 8;
    int d4 = threadIdx.x << 2;
    float4 g0a = *(const float4*)(gw + d4);
    float4 g0b = *(const float4*)(gw + Dd + d4);
    float4 g2a = *(const float4*)(gw + 3072 + d4);
    float4 g2b = *(const float4*)(gw + 3072 + Dd + d4);
    float4 k1 = *(const float4*)(kvecs + Dd + d4);
    float4 k3 = *(const float4*)(kvecs + 3 * Dd + d4);
    float4 gs0, gs2;
    gs0.x=g0a.x+g0b.x; gs0.y=g0a.y+g0b.y; gs0.z=g0a.z+g0b.z; gs0.w=g0a.w+g0b.w;
    gs2.x=g2a.x+g2b.x; gs2.y=g2a.y+g2b.y; gs2.z=g2a.z+g2b.z; gs2.w=g2a.w+g2b.w;
    float4 x = *(const float4*)(x0 + r0 * Dd + d4);
    for (int i = 0; i < 8; ++i) {
        float4 xn = make_float4(0.f,0.f,0.f,0.f);
        if (i < 7) xn = *(const float4*)(x0 + (r0 + i + 1) * Dd + d4);
        float4 p;
        p.x = x.x*gs0.x + x.y*gs0.y + x.z*gs0.z + x.w*gs0.w;
        p.y = x.x*k1.x + x.y*k1.y + x.z*k1.z + x.w*k1.w;
        p.z = x.x*gs2.x + x.y*gs2.y + x.z*gs2.z + x.w*gs2.w;
        p.w = x.x*k3.x + x.y*k3.y + x.z*k3.z + x.w*k3.w;
        p = blk_sum3_v4(p, sh);
        if (threadIdx.x == 0) *(float4*)(xd + (r0 + i) * 4) = p;
        x = xn;
    }
}

// ---------- attention over relations (N=C=97) + combine; inline P-gate for phase 1 ----------
__global__ void attnP_kernel(const float* __restrict__ pdots, const float* __restrict__ sc,
                             const float* __restrict__ gb, const float* __restrict__ p0,
                             const float* __restrict__ av1, float alpha,
                             float* __restrict__ g1buf, float* __restrict__ xaP,
                             float* __restrict__ zeroT, int phase) {
    __shared__ float lw[97];
    __shared__ float sh[12];
    int b = blockIdx.x, t = threadIdx.x;
    float v = -3.0e38f, g1 = 0.f;
    if (t < Cc) {
        if (phase == 0) v = pdots[t];
        else {
            g1 = sigm(pdots[194 + t] + sc[128 + b] + gb[1]);
            g1buf[(size_t)b * Cc + t] = g1;
            v = 2.f * pdots[97 + t] + g1 * sc[160 + b];
        }
    }
    float m = v;
#pragma unroll
    for (int o = 32; o > 0; o >>= 1) m = fmaxf(m, __shfl_down(m, o, 64));
    if ((t & 63) == 0) sh[t >> 6] = m;
    __syncthreads();
    m = fmaxf(fmaxf(sh[0], sh[1]), sh[2]);
    __syncthreads();
    float e = (t < Cc) ? expf(v - m) : 0.f;
    float s = blk_sum3(e, sh);
    float wc = e / s;
    if (t < Cc) lw[t] = wc;
    float cg = blk_sum3(wc * g1, sh);   // 0 for phase 0 (g1=0); syncs lw too
    int d4 = t << 2;
    *(float4*)(zeroT + (size_t)b * Dd + d4) = make_float4(0.f,0.f,0.f,0.f);
    float4 acc = make_float4(0.f,0.f,0.f,0.f);
    for (int c = 0; c < Cc; ++c) {
        float w = lw[c];
        float4 pv = *(const float4*)(p0 + (size_t)c * Dd + d4);
        acc.x += w*pv.x; acc.y += w*pv.y; acc.z += w*pv.z; acc.w += w*pv.w;
    }
    float4 o;
    o.x = alpha*acc.x; o.y = alpha*acc.y; o.z = alpha*acc.z; o.w = alpha*acc.w;
    if (phase == 1) {
        float4 a = *(const float4*)(av1 + (size_t)b * Dd + d4);
        o.x += cg*a.x; o.y += cg*a.y; o.z += cg*a.z; o.w += cg*a.w;
    }
    *(float4*)(xaP + (size_t)b * Dd + d4) = o;
}

// ---------- GEMV bank + fused scalar dots of the result ----------
// out[b,:] += xs@W ; xs = gamma*S[b] + multA*coefA[b]*avA[b] + multB*coefB[b]*avB[b]
// dots: dout[v*32+b] += sum_j (this block's partial out_j)*(dva[j](+dvb[j]))
__global__ void mm32_kernel(const float* __restrict__ S, float gamma,
        const float* __restrict__ avA, const float* __restrict__ coefA, float multA,
        const float* __restrict__ avB, const float* __restrict__ coefB, float multB,
        const float* __restrict__ W, const float* __restrict__ bias, float* __restrict__ out,
        const float* d0a, const float* d0b, const float* d1a, const float* d1b,
        const float* d2a, const float* d2b, const float* d3a, const float* d3b,
        float* __restrict__ dout, int ndots) {
    __shared__ float xs[192];
    __shared__ float shr[4];
    int t = threadIdx.x;
    int b = blockIdx.y, seg = blockIdx.z;
    if (t < 192) {
        int d = seg * 192 + t;
        float v = gamma * S[(size_t)b * Dd + d];
        if (avA) v += multA * coefA[b] * avA[(size_t)b * Dd + d];
        if (avB) v += multB * coefB[b] * avB[(size_t)b * Dd + d];
        xs[t] = v;
    }
    __syncthreads();
    int j = blockIdx.x * 256 + t;
    float acc = (seg == 0 && bias) ? bias[j] : 0.f;
    const float* wp = W + (size_t)(seg * 192) * Dd + j;
#pragma unroll 4
    for (int dd = 0; dd < 192; ++dd) acc += xs[dd] * wp[(size_t)dd * Dd];
    atomicAdd(&out[(size_t)b * Dd + j], acc);
    for (int v = 0; v < ndots; ++v) {
        const float *va, *vbp;
        switch (v) { case 0: va=d0a; vbp=d0b; break; case 1: va=d1a; vbp=d1b; break;
                     case 2: va=d2a; vbp=d2b; break; default: va=d3a; vbp=d3b; break; }
        float wv = va[j] + (vbp ? vbp[j] : 0.f);
        float p = blk_sum4(acc * wv, shr);
        if (t == 0) atomicAdd(&dout[v * 32 + b], p);
    }
}

// ---------- fused X-gate + masked softmax over L + coef sums + zero targets ----------
__global__ void softgate_kernel(const float* __restrict__ xd, const float* __restrict__ scc,
        float* __restrict__ scw, const float* __restrict__ gb, const int* __restrict__ mask,
        float* __restrict__ gx1, float* __restrict__ gx2, float* __restrict__ awb, int phase,
        float* z0, float* z1, float* z2, float* z3) {
    __shared__ float sh[4];
    int b = blockIdx.x, t = threadIdx.x;
    float ks[2], ga[2] = {0.f,0.f}, gbv[2] = {0.f,0.f};
#pragma unroll
    for (int i = 0; i < 2; ++i) {
        int l = t + (i << 8);
        size_t r = (size_t)b * Ls + l;
        float4 x = *(const float4*)(xd + r * 4);
        if (phase == 0) {
            float g = sigm(x.x + scc[b] + gb[0]);
            gx1[r] = g;
            ga[i] = g;
            ks[i] = 2.f * x.y + g * scc[32 + b];
        } else {
            float gp = gx1[r];
            float g = sigm(2.f * x.z + gp * scc[64 + b] + scc[224 + b] + gb[2]);
            gx2[r] = g;
            ga[i] = gp; gbv[i] = g;
            ks[i] = 4.f * x.w + 2.f * gp * scc[96 + b] + g * scc[256 + b];
        }
        if (mask[r] == 0) ks[i] = -1e9f;
    }
    float mx = fmaxf(ks[0], ks[1]);
#pragma unroll
    for (int o = 32; o > 0; o >>= 1) mx = fmaxf(mx, __shfl_down(mx, o, 64));
    if ((t & 63) == 0) sh[t >> 6] = mx;
    __syncthreads();
    mx = fmaxf(fmaxf(sh[0], sh[1]), fmaxf(sh[2], sh[3]));
    __syncthreads();
    float e0 = expf(ks[0] - mx), e1 = expf(ks[1] - mx);
    float s = blk_sum4(e0 + e1, sh);
    float inv = 1.f / s;
    float w0 = e0 * inv, w1 = e1 * inv;
    awb[(size_t)b * Ls + t] = w0;
    awb[(size_t)b * Ls + t + 256] = w1;
    float ca = blk_sum4(w0 * ga[0] + w1 * ga[1], sh);
    if (phase == 0) {
        if (t == 0) scw[320 + b] = ca;
    } else {
        if (t == 0) scw[352 + b] = ca;
        float cb = blk_sum4(w0 * gbv[0] + w1 * gbv[1], sh);
        if (t == 0) scw[384 + b] = cb;
    }
    for (int d = t; d < Dd; d += 256) {
        if (z0) z0[(size_t)b * Dd + d] = 0.f;
        if (z1) z1[(size_t)b * Dd + d] = 0.f;
        if (z2) z2[(size_t)b * Dd + d] = 0.f;
        if (z3) z3[(size_t)b * Dd + d] = 0.f;
    }
}

// ---------- stream x0: S += sum_l w*x0 (+ optional pos sums); 32 rows/block ----------
__global__ void passX_kernel(const float* __restrict__ x0, const float* __restrict__ w,
                             const float* __restrict__ pos1, const float* __restrict__ pos2,
                             float* __restrict__ S, float* __restrict__ xp1, float* __restrict__ xp2) {
    int b = blockIdx.x, seg = blockIdx.y;
    int l0 = seg * 32;
    int d4 = threadIdx.x << 2;
    const float* xb = x0 + ((size_t)b * Ls + l0) * Dd + d4;
    float4 as = make_float4(0.f,0.f,0.f,0.f);
    float4 a1 = make_float4(0.f,0.f,0.f,0.f);
    float4 a2 = make_float4(0.f,0.f,0.f,0.f);
    for (int l = 0; l < 32; ++l) {
        float4 xv = *(const float4*)(xb + (size_t)l * Dd);
        float wv = w[(size_t)b * Ls + l0 + l];
        as.x += wv*xv.x; as.y += wv*xv.y; as.z += wv*xv.z; as.w += wv*xv.w;
        if (pos1) {
            float p1 = pos1[(size_t)b * Ls + l0 + l], p2 = pos2[(size_t)b * Ls + l0 + l];
            a1.x += p1*xv.x; a1.y += p1*xv.y; a1.z += p1*xv.z; a1.w += p1*xv.w;
            a2.x += p2*xv.x; a2.y += p2*xv.y; a2.z += p2*xv.z; a2.w += p2*xv.w;
        }
    }
    float* ds = S + (size_t)b * Dd + d4;
    atomicAdd(ds+0, as.x); atomicAdd(ds+1, as.y); atomicAdd(ds+2, as.z); atomicAdd(ds+3, as.w);
    if (pos1) {
        float* d1 = xp1 + (size_t)b * Dd + d4;
        float* d2 = xp2 + (size_t)b * Dd + d4;
        atomicAdd(d1+0, a1.x); atomicAdd(d1+1, a1.y); atomicAdd(d1+2, a1.z); atomicAdd(d1+3, a1.w);
        atomicAdd(d2+0, a2.x); atomicAdd(d2+1, a2.y); atomicAdd(d2+2, a2.z); atomicAdd(d2+3, a2.w);
    }
}

// ---------- pool coefficients + denominators; zero aw12 ----------
__global__ void poolcoef_kernel(const float* __restrict__ pos1, const float* __restrict__ pos2,
                                const float* __restrict__ gx1, const float* __restrict__ gx2,
                                float* __restrict__ sc, float* __restrict__ aw12) {
    __shared__ float sh[4];
    int b = blockIdx.x, t = threadIdx.x;
    float p1a = pos1[(size_t)b*Ls + t], p1b = pos1[(size_t)b*Ls + t + 256];
    float p2a = pos2[(size_t)b*Ls + t], p2b = pos2[(size_t)b*Ls + t + 256];
    float g1a = gx1[(size_t)b*Ls + t], g1b = gx1[(size_t)b*Ls + t + 256];
    float g2a = gx2[(size_t)b*Ls + t], g2b = gx2[(size_t)b*Ls + t + 256];
    float s1 = blk_sum4(p1a + p1b, sh);
    float s2 = blk_sum4(p2a + p2b, sh);
    float c11 = blk_sum4(p1a*g1a + p1b*g1b, sh);
    float c12 = blk_sum4(p1a*g2a + p1b*g2b, sh);
    float c21 = blk_sum4(p2a*g1a + p2b*g1b, sh);
    float c22 = blk_sum4(p2a*g2a + p2b*g2b, sh);
    if (t == 0) {
        sc[448+b] = c11; sc[480+b] = c12; sc[512+b] = c21; sc[544+b] = c22;
        sc[576+b] = 1.f / s1; sc[608+b] = 1.f / s2;
    }
    for (int d = t; d < Dd; d += 256) {
        aw12[(size_t)b * Dd + d] = 0.f;
        aw12[(size_t)(32 + b) * Dd + d] = 0.f;
    }
}

// ---------- ge[b,j] = e1·W1 + e2·W2 + fc1b; grid (3,32,4) ----------
__global__ void ge_kernel(const float* __restrict__ xp1, const float* __restrict__ xp2,
                          const float* __restrict__ avx1, const float* __restrict__ avx2,
                          const float* __restrict__ sc, const float* __restrict__ fc1w,
                          const float* __restrict__ fc1b, float* __restrict__ geb) {
    __shared__ float es1[192], es2[192];
    int t = threadIdx.x;
    int b = blockIdx.y, seg = blockIdx.z;
    if (t < 192) {
        int d = seg * 192 + t;
        float a1 = avx1[(size_t)b * Dd + d], a2 = avx2[(size_t)b * Dd + d];
        es1[t] = (4.f * xp1[(size_t)b * Dd + d] + 2.f * sc[448+b] * a1 + sc[480+b] * a2) * sc[576+b];
        es2[t] = (4.f * xp2[(size_t)b * Dd + d] + 2.f * sc[512+b] * a1 + sc[544+b] * a2) * sc[608+b];
    }
    __syncthreads();
    int j = blockIdx.x * 256 + t;
    float a1 = 0.f, a2 = 0.f;
    const float* w1 = fc1w + (size_t)(Dd + seg * 192) * Dd + j;
    const float* w2 = fc1w + (size_t)(2 * Dd + seg * 192) * Dd + j;
#pragma unroll 4
    for (int dd = 0; dd < 192; ++dd) {
        a1 += es1[dd] * w1[(size_t)dd * Dd];
        a2 += es2[dd] * w2[(size_t)dd * Dd];
    }
    float res = a1 + a2 + (seg == 0 ? fc1b[j] : 0.f);
    atomicAdd(&geb[(size_t)b * Dd + j], res);
}

// ---------- logits ----------
__global__ void logits_kernel(const float* __restrict__ g1buf, const float* __restrict__ pdots,
                              const float* __restrict__ sc, const float* __restrict__ gb,
                              const float* __restrict__ pp, const float* __restrict__ aw12,
                              const float* __restrict__ geb, const float* __restrict__ fc2w,
                              const float* __restrict__ fc2b, float* __restrict__ out) {
    __shared__ float sh[3];
    int r = blockIdx.x;
    int b = r / Cc, c = r - b * Cc;
    float g1 = g1buf[r];
    float g2 = sigm(2.f * pdots[291 + c] + g1 * sc[192 + b] + sc[288 + b] + gb[3]);
    int d4 = threadIdx.x << 2;
    float4 ppv = *(const float4*)(pp + (size_t)c * Dd + d4);
    float4 a1v = *(const float4*)(aw12 + (size_t)b * Dd + d4);
    float4 a2v = *(const float4*)(aw12 + (size_t)(32 + b) * Dd + d4);
    float4 gev = *(const float4*)(geb + (size_t)b * Dd + d4);
    float4 fv  = *(const float4*)(fc2w + d4);
    float t = tanhf(4.f*ppv.x + 2.f*g1*a1v.x + g2*a2v.x + gev.x) * fv.x
            + tanhf(4.f*ppv.y + 2.f*g1*a1v.y + g2*a2v.y + gev.y) * fv.y
            + tanhf(4.f*ppv.z + 2.f*g1*a1v.z + g2*a2v.z + gev.z) * fv.z
            + tanhf(4.f*ppv.w + 2.f*g1*a1v.w + g2*a2v.w + gev.w) * fv.w;
    t = blk_sum3(t, sh);
    if (threadIdx.x == 0) out[r] = sigm(t + fc2b[0]);
}

__global__ void argmax_kernel(const float* __restrict__ lg, float* __restrict__ pred) {
    int b = threadIdx.x;
    if (b < Bb) {
        const float* row = lg + (size_t)b * Cc;
        float best = row[0];
        int bi = 0;
        for (int c = 1; c < Cc; ++c) {
            float v = row[c];
            if (v > best) { best = v; bi = c; }
        }
        pred[b] = (float)bi;
    }
}

extern "C" void kernel_launch(void* const* d_in, const int* in_sizes, int n_in,
                              void* d_out, int out_size, void* d_ws, size_t ws_size,
                              hipStream_t stream) {
    const float* x0    = (const float*)d_in[0];
    const float* pos1  = (const float*)d_in[1];
    const float* pos2  = (const float*)d_in[2];
    const int*   mask  = (const int*)d_in[3];
    const float* emb   = (const float*)d_in[4];
    const float* rel_w = (const float*)d_in[5];
    const float* rel_b = (const float*)d_in[6];
    // qw(7), qb(8): dead — softmax shift-invariance; kb(10), sb(14): dead — row-constant
    const float* kw    = (const float*)d_in[9];
    const float* vw    = (const float*)d_in[11];
    const float* vb    = (const float*)d_in[12];
    const float* sw    = (const float*)d_in[13];
    const float* gw    = (const float*)d_in[15];
    const float* gb    = (const float*)d_in[16];
    const float* fc1w  = (const float*)d_in[17];
    const float* fc1b  = (const float*)d_in[18];
    const float* fc2w  = (const float*)d_in[19];
    const float* fc2b  = (const float*)d_in[20];
    float* out = (float*)d_out;

    const float* gw0a = gw;            // gw slices: [li*2+ra][0:768 | 768:1536]
    const float* gw1a = gw + 1536;     const float* gw1b = gw + 1536 + Dd;
    const float* gw2a = gw + 3072;     const float* gw2b = gw + 3072 + Dd;
    const float* gw3a = gw + 4608;     const float* gw3b = gw + 4608 + Dd;

    float* ws = (float*)d_ws;
    size_t off = 0;
    // [p0b | pp | sc] = contiguous zero region (149632 floats), zeroed by kvec
    float* p0b   = ws + off; off += (size_t)Cc * Dd;
    float* pp    = ws + off; off += (size_t)Cc * Dd;
    float* sc    = ws + off; off += 640;
    int zn = (int)off;
    float* kvecs = ws + off; off += (size_t)4 * Dd;
    float* pdots = ws + off; off += 388;
    float* xd    = ws + off; off += (size_t)Bb * Ls * 4;
    float* gx1   = ws + off; off += (size_t)Bb * Ls;
    float* gx2   = ws + off; off += (size_t)Bb * Ls;
    float* awb   = ws + off; off += (size_t)Bb * Ls;
    float* g1buf = ws + off; off += (size_t)Bb * Cc;
    float* xaPb  = ws + off; off += (size_t)Bb * Dd;
    float* avx1  = ws + off; off += (size_t)Bb * Dd;
    float* avx2  = ws + off; off += (size_t)Bb * Dd;
    float* av12  = ws + off; off += (size_t)2 * Bb * Dd;
    float* aw12  = ws + off; off += (size_t)2 * Bb * Dd;
    float* S0    = ws + off; off += (size_t)Bb * Dd;
    float* xp1   = ws + off; off += (size_t)Bb * Dd;
    float* xp2   = ws + off; off += (size_t)Bb * Dd;
    float* geb   = ws + off; off += (size_t)Bb * Dd;
    float* av1 = av12;
    float* av2 = av12 + (size_t)Bb * Dd;
    const float* k1v = kvecs + Dd;
    const float* k2v = kvecs + 2 * Dd;
    const float* k3v = kvecs + 3 * Dd;

    // 1: kvecs + zero [p0b|pp|sc]
    kvec_kernel<<<dim3(Dd, 4), 256, 0, stream>>>(kw, sw, kvecs, ws, zn);
    // 2-3: split-K GEMMs (192 blocks each)
    sgemm_splitk_kernel<<<dim3(12, 2, 8), 256, 0, stream>>>(emb, rel_w, rel_b, p0b, Cc, Dd, Dd, 96);
    sgemm_splitk_kernel<<<dim3(12, 2, 8), 256, 0, stream>>>(p0b, fc1w, nullptr, pp, Cc, Dd, Dd, 96);
    // 4: pdots = p0·{kvec0, kvec2, gw1a+gw1b, gw3a+gw3b}
    rowdots_kernel<<<dim3(Cc, 4), 256, 0, stream>>>(p0b,
        kvecs, nullptr, k2v, nullptr, gw1a, gw1b, gw3a, gw3b, pdots, Cc);
    // 5: xd = x0·{gwsum0, kvec1, gwsum2, kvec3}
    xdots_kernel<<<Bb * Ls / 8, 192, 0, stream>>>(x0, kvecs, gw, xd);

    // ---- layer 0, RA1
    attnP_kernel<<<Bb, 192, 0, stream>>>(pdots, sc, gb, p0b, nullptr, 1.f, nullptr, xaPb, avx1, 0);
    mm32_kernel<<<dim3(3, Bb, 4), 256, 0, stream>>>(xaPb, 1.f, nullptr, nullptr, 0.f,
        nullptr, nullptr, 0.f, vw, vb, avx1,
        gw0a, nullptr, k1v, nullptr, gw2a, gw2b, k3v, nullptr, sc, 4);
    softgate_kernel<<<Bb, 256, 0, stream>>>(xd, sc, sc, gb, mask, gx1, nullptr, awb, 0,
        S0, xp1, xp2, av1);
    // ---- layer 0, RA2
    passX_kernel<<<dim3(Bb, 16), 192, 0, stream>>>(x0, awb, pos1, pos2, S0, xp1, xp2);
    mm32_kernel<<<dim3(3, Bb, 4), 256, 0, stream>>>(S0, 2.f, avx1, sc + 320, 1.f,
        nullptr, nullptr, 0.f, vw + (size_t)1*Dd*Dd, vb + Dd, av1,
        gw1a, nullptr, k2v, nullptr, gw3a, gw3b, nullptr, nullptr, sc + 128, 3);
    // ---- layer 1, RA1 (inline P-gate)
    attnP_kernel<<<Bb, 192, 0, stream>>>(pdots, sc, gb, p0b, av1, 2.f, g1buf, xaPb, avx2, 1);
    mm32_kernel<<<dim3(3, Bb, 4), 256, 0, stream>>>(xaPb, 1.f, nullptr, nullptr, 0.f,
        nullptr, nullptr, 0.f, vw + (size_t)2*Dd*Dd, vb + 2*Dd, avx2,
        gw2a, nullptr, k3v, nullptr, nullptr, nullptr, nullptr, nullptr, sc + 224, 2);
    softgate_kernel<<<Bb, 256, 0, stream>>>(xd, sc, sc, gb, mask, gx1, gx2, awb, 1,
        S0, av2, geb, nullptr);
    // ---- layer 1, RA2
    passX_kernel<<<dim3(Bb, 16), 192, 0, stream>>>(x0, awb, nullptr, nullptr, S0, nullptr, nullptr);
    mm32_kernel<<<dim3(3, Bb, 4), 256, 0, stream>>>(S0, 4.f, avx1, sc + 352, 2.f,
        avx2, sc + 384, 1.f, vw + (size_t)3*Dd*Dd, vb + 3*Dd, av2,
        gw3a, nullptr, nullptr, nullptr, nullptr, nullptr, nullptr, nullptr, sc + 288, 1);

    // ---- classifier head
    poolcoef_kernel<<<Bb, 256, 0, stream>>>(pos1, pos2, gx1, gx2, sc, aw12);
    ge_kernel<<<dim3(3, Bb, 4), 256, 0, stream>>>(xp1, xp2, avx1, avx2, sc, fc1w, fc1b, geb);
    mm32_kernel<<<dim3(3, 2 * Bb, 4), 256, 0, stream>>>(av12, 1.f, nullptr, nullptr, 0.f,
        nullptr, nullptr, 0.f, fc1w, nullptr, aw12,
        nullptr, nullptr, nullptr, nullptr, nullptr, nullptr, nullptr, nullptr, nullptr, 0);
    logits_kernel<<<Bb * Cc, 192, 0, stream>>>(g1buf, pdots, sc, gb, pp, aw12, geb,
        fc2w, fc2b, out);
    argmax_kernel<<<1, 64, 0, stream>>>(out, out + Bb * Cc);
}

// Round 6
// 383.902 us; speedup vs baseline: 2.6481x; 1.0671x over previous
//
#include <hip/hip_runtime.h>
#include <math.h>

#define NBLK 512
#define NTHR 256
static const int Bb = 32, Ls = 512, Dd = 768, Cc = 97;

struct KArgs {
    const float *x0, *pos1, *pos2;
    const int* mask;
    const float *emb, *rel_w, *rel_b, *kw, *vw, *vb, *sw, *gw, *gb;
    const float *fc1w, *fc1b, *fc2w, *fc2b;
    float* out;
    float *p0b, *pp, *sc, *avx1, *avx2, *av1, *av2, *aw1, *aw2, *S0, *S1, *xp1, *xp2, *geb;
    float *kvecs, *pdots, *g1buf, *xd, *gx1, *gx2, *awb;
    float* zbase;
    int zcount;
};

__device__ __forceinline__ float sigm(float x) { return 1.f / (1.f + expf(-x)); }

__device__ __forceinline__ float wred(float v) {
#pragma unroll
    for (int o = 32; o > 0; o >>= 1) v += __shfl_down(v, o, 64);
    return v;
}

__device__ __forceinline__ float blk_sum4(float v, float* shr) {
    v = wred(v);
    int t = threadIdx.x;
    if ((t & 63) == 0) shr[t >> 6] = v;
    __syncthreads();
    float r = shr[0] + shr[1] + shr[2] + shr[3];
    __syncthreads();
    return r;
}

// ---- split-K SGEMM tile: C += A[:,kb:kb+KC]@W[kb:kb+KC,:] (+bias at bz==0); C pre-zeroed
__device__ void sgemm_dev(const float* __restrict__ A, const float* __restrict__ W,
                          const float* __restrict__ bias, float* __restrict__ C,
                          int M, int N, int K, int KC, int bx, int by, int bz,
                          float* As, float* Ws) {
    int tid = threadIdx.x;
    int tx = tid & 15, ty = tid >> 4;
    int bn = bx * 64, bm = by * 64;
    int kb = bz * KC;
    int arow = tid >> 2, akq = (tid & 3) << 2;
    int wrow = tid >> 4, wcol = (tid & 15) << 2;
    int gar = bm + arow;
    bool aval = gar < M;
    const float* Ap = A + (size_t)gar * K + kb + akq;
    const float* Wp = W + (size_t)(kb + wrow) * N + bn + wcol;
    float acc[4][4] = {{0.f}};
    float4 a4 = make_float4(0.f, 0.f, 0.f, 0.f);
    if (aval) a4 = *(const float4*)Ap;
    float4 w4 = *(const float4*)Wp;
    for (int k0 = 0; k0 < KC; k0 += 16) {
        __syncthreads();
        As[(akq + 0) * 64 + arow] = a4.x; As[(akq + 1) * 64 + arow] = a4.y;
        As[(akq + 2) * 64 + arow] = a4.z; As[(akq + 3) * 64 + arow] = a4.w;
        *(float4*)&Ws[wrow * 64 + wcol] = w4;
        __syncthreads();
        if (k0 + 16 < KC) {
            if (aval) a4 = *(const float4*)(Ap + k0 + 16);
            w4 = *(const float4*)(Wp + (size_t)(k0 + 16) * N);
        }
#pragma unroll
        for (int kk = 0; kk < 16; ++kk) {
            float4 a = *(const float4*)&As[kk * 64 + (ty << 2)];
            float4 b = *(const float4*)&Ws[kk * 64 + (tx << 2)];
            acc[0][0]+=a.x*b.x; acc[0][1]+=a.x*b.y; acc[0][2]+=a.x*b.z; acc[0][3]+=a.x*b.w;
            acc[1][0]+=a.y*b.x; acc[1][1]+=a.y*b.y; acc[1][2]+=a.y*b.z; acc[1][3]+=a.y*b.w;
            acc[2][0]+=a.z*b.x; acc[2][1]+=a.z*b.y; acc[2][2]+=a.z*b.z; acc[2][3]+=a.z*b.w;
            acc[3][0]+=a.w*b.x; acc[3][1]+=a.w*b.y; acc[3][2]+=a.w*b.z; acc[3][3]+=a.w*b.w;
        }
    }
    int gc = bn + (tx << 2);
    float4 bz4 = make_float4(0.f, 0.f, 0.f, 0.f);
    if (bz == 0 && bias) bz4 = *(const float4*)(bias + gc);
#pragma unroll
    for (int i = 0; i < 4; ++i) {
        int gr = bm + (ty << 2) + i;
        if (gr < M) {
            float* cp = C + (size_t)gr * N + gc;
            atomicAdd(cp + 0, acc[i][0] + bz4.x); atomicAdd(cp + 1, acc[i][1] + bz4.y);
            atomicAdd(cp + 2, acc[i][2] + bz4.z); atomicAdd(cp + 3, acc[i][3] + bz4.w);
        }
    }
}

// ---- fused relation-attention + V-GEMV (+scalar dots); job jlin in [0,384)
__device__ void attn_gemv(const KArgs& a, int phase, int jlin,
                          float* xs, float* lw, float* shr) {
    int t = threadIdx.x;
    int jseg = jlin % 3, b = (jlin / 3) % 32, seg = jlin / 96;
    float v = -3.0e38f, g1 = 0.f;
    if (t < Cc) {
        if (phase == 0) v = a.pdots[t];
        else {
            g1 = sigm(a.pdots[194 + t] + a.sc[128 + b] + a.gb[1]);
            v = 2.f * a.pdots[97 + t] + g1 * a.sc[160 + b];
        }
    }
    if (phase == 1 && jseg == 0 && seg == 0 && t < Cc) a.g1buf[(size_t)b * Cc + t] = g1;
    float m = v;
#pragma unroll
    for (int o = 32; o > 0; o >>= 1) m = fmaxf(m, __shfl_down(m, o, 64));
    if ((t & 63) == 0) shr[t >> 6] = m;
    __syncthreads();
    m = fmaxf(fmaxf(shr[0], shr[1]), fmaxf(shr[2], shr[3]));
    __syncthreads();
    float e = (t < Cc) ? expf(v - m) : 0.f;
    float s = blk_sum4(e, shr);
    float wc = e / s;
    if (t < Cc) lw[t] = wc;
    float cg1 = blk_sum4(wc * g1, shr);   // also publishes lw
    float alpha = (phase == 0) ? 1.f : 2.f;
    if (t < 192) {
        int d = seg * 192 + t;
        const float* pc = a.p0b + d;
        float acc2 = 0.f;
        for (int c = 0; c < Cc; ++c) acc2 += lw[c] * pc[(size_t)c * Dd];
        float val = alpha * acc2;
        if (phase == 1) val += cg1 * a.av1[(size_t)b * Dd + d];
        xs[t] = val;
    }
    __syncthreads();
    const float* W = a.vw + (size_t)(phase == 0 ? 0 : 2) * Dd * Dd;
    const float* bias = a.vb + (phase == 0 ? 0 : 2) * Dd;
    float* outp = (phase == 0) ? a.avx1 : a.avx2;
    int j = jseg * 256 + t;
    float acc = (seg == 0) ? bias[j] : 0.f;
    const float* wp = W + (size_t)(seg * 192) * Dd + j;
#pragma unroll 4
    for (int dd = 0; dd < 192; ++dd) acc += xs[dd] * wp[(size_t)dd * Dd];
    atomicAdd(&outp[(size_t)b * Dd + j], acc);
    const float* da[4]; const float* db[4]; int nd; float* dout;
    if (phase == 0) {
        da[0]=a.gw;          db[0]=nullptr;
        da[1]=a.kvecs+Dd;    db[1]=nullptr;
        da[2]=a.gw+3072;     db[2]=a.gw+3840;
        da[3]=a.kvecs+3*Dd;  db[3]=nullptr;
        nd = 4; dout = a.sc;
    } else {
        da[0]=a.gw+3072;     db[0]=nullptr;
        da[1]=a.kvecs+3*Dd;  db[1]=nullptr;
        nd = 2; dout = a.sc + 224;
    }
    for (int vv = 0; vv < nd; ++vv) {
        float wv = da[vv][j] + (db[vv] ? db[vv][j] : 0.f);
        float p = blk_sum4(acc * wv, shr);
        if (t == 0) atomicAdd(&dout[vv * 32 + b], p);
    }
}

// ---- GEMV bank: out[b,:] += xs@W, xs = gamma*S + multA*coefA[b]*avA + multB*coefB[b]*avB
__device__ void mm_dev(const KArgs& a, int jlin, const float* S, float gamma,
                       const float* avA, const float* coefA, float multA,
                       const float* avB, const float* coefB, float multB,
                       const float* W, const float* bias, float* outp,
                       int ndots, const float* d0a, const float* d0b,
                       const float* d1a, const float* d2a, const float* d2b,
                       float* dout, float* xs, float* shr) {
    int t = threadIdx.x;
    int jseg = jlin % 3, b = (jlin / 3) % 32, seg = jlin / 96;
    if (t < 192) {
        int d = seg * 192 + t;
        float v = gamma * S[(size_t)b * Dd + d];
        if (avA) v += multA * coefA[b] * avA[(size_t)b * Dd + d];
        if (avB) v += multB * coefB[b] * avB[(size_t)b * Dd + d];
        xs[t] = v;
    }
    __syncthreads();
    int j = jseg * 256 + t;
    float acc = (seg == 0 && bias) ? bias[j] : 0.f;
    const float* wp = W + (size_t)(seg * 192) * Dd + j;
#pragma unroll 4
    for (int dd = 0; dd < 192; ++dd) acc += xs[dd] * wp[(size_t)dd * Dd];
    atomicAdd(&outp[(size_t)b * Dd + j], acc);
    if (ndots > 0) {
        float wv = d0a[j] + (d0b ? d0b[j] : 0.f);
        float p = blk_sum4(acc * wv, shr);
        if (t == 0) atomicAdd(&dout[b], p);
    }
    if (ndots > 1) {
        float p = blk_sum4(acc * d1a[j], shr);
        if (t == 0) atomicAdd(&dout[32 + b], p);
    }
    if (ndots > 2) {
        float wv = d2a[j] + (d2b ? d2b[j] : 0.f);
        float p = blk_sum4(acc * wv, shr);
        if (t == 0) atomicAdd(&dout[64 + b], p);
    }
    __syncthreads();
}

// ---- ge: geb[b,:] += e1@W1 + e2@W2 + fc1b
__device__ void ge_dev(const KArgs& a, int jlin, float* xs, float* xs2) {
    __syncthreads();
    int t = threadIdx.x;
    int jseg = jlin % 3, b = (jlin / 3) % 32, seg = jlin / 96;
    if (t < 192) {
        int d = seg * 192 + t;
        float a1 = a.avx1[(size_t)b * Dd + d], a2 = a.avx2[(size_t)b * Dd + d];
        xs[t]  = (4.f * a.xp1[(size_t)b * Dd + d] + 2.f * a.sc[448 + b] * a1 + a.sc[480 + b] * a2) * a.sc[576 + b];
        xs2[t] = (4.f * a.xp2[(size_t)b * Dd + d] + 2.f * a.sc[512 + b] * a1 + a.sc[544 + b] * a2) * a.sc[608 + b];
    }
    __syncthreads();
    int j = jseg * 256 + t;
    float a1 = 0.f, a2 = 0.f;
    const float* w1 = a.fc1w + (size_t)(Dd + seg * 192) * Dd + j;
    const float* w2 = a.fc1w + (size_t)(2 * Dd + seg * 192) * Dd + j;
#pragma unroll 4
    for (int dd = 0; dd < 192; ++dd) {
        a1 += xs[dd] * w1[(size_t)dd * Dd];
        a2 += xs2[dd] * w2[(size_t)dd * Dd];
    }
    float res = a1 + a2 + (seg == 0 ? a.fc1b[j] : 0.f);
    atomicAdd(&a.geb[(size_t)b * Dd + j], res);
}

// ---- softgate: gate coeffs + masked softmax over L (+ pool coeffs at phase 1)
__device__ void softgate_dev(const KArgs& a, int phase, int b, float* shr) {
    int t = threadIdx.x;
    float ks[2], ga[2] = {0.f, 0.f}, gb2[2] = {0.f, 0.f};
#pragma unroll
    for (int i = 0; i < 2; ++i) {
        int l = t + (i << 8);
        size_t r = (size_t)b * Ls + l;
        float4 x = *(const float4*)(a.xd + r * 4);
        if (phase == 0) {
            float g = sigm(x.x + a.sc[b] + a.gb[0]);
            a.gx1[r] = g;
            ga[i] = g;
            ks[i] = 2.f * x.y + g * a.sc[32 + b];
        } else {
            float gp = a.gx1[r];
            float g = sigm(2.f * x.z + gp * a.sc[64 + b] + a.sc[224 + b] + a.gb[2]);
            a.gx2[r] = g;
            ga[i] = gp; gb2[i] = g;
            ks[i] = 4.f * x.w + 2.f * gp * a.sc[96 + b] + g * a.sc[256 + b];
        }
        if (a.mask[r] == 0) ks[i] = -1e9f;
    }
    float mx = fmaxf(ks[0], ks[1]);
#pragma unroll
    for (int o = 32; o > 0; o >>= 1) mx = fmaxf(mx, __shfl_down(mx, o, 64));
    if ((t & 63) == 0) shr[t >> 6] = mx;
    __syncthreads();
    mx = fmaxf(fmaxf(shr[0], shr[1]), fmaxf(shr[2], shr[3]));
    __syncthreads();
    float e0 = expf(ks[0] - mx), e1 = expf(ks[1] - mx);
    float s = blk_sum4(e0 + e1, shr);
    float inv = 1.f / s;
    float w0 = e0 * inv, w1 = e1 * inv;
    a.awb[(size_t)b * Ls + t] = w0;
    a.awb[(size_t)b * Ls + t + 256] = w1;
    float ca = blk_sum4(w0 * ga[0] + w1 * ga[1], shr);
    if (phase == 0) {
        if (t == 0) a.sc[320 + b] = ca;
    } else {
        if (t == 0) a.sc[352 + b] = ca;
        float cb = blk_sum4(w0 * gb2[0] + w1 * gb2[1], shr);
        if (t == 0) a.sc[384 + b] = cb;
        float q1a = a.pos1[(size_t)b * Ls + t], q1b = a.pos1[(size_t)b * Ls + t + 256];
        float q2a = a.pos2[(size_t)b * Ls + t], q2b = a.pos2[(size_t)b * Ls + t + 256];
        float s1 = blk_sum4(q1a + q1b, shr);
        float s2 = blk_sum4(q2a + q2b, shr);
        float c11 = blk_sum4(q1a * ga[0] + q1b * ga[1], shr);
        float c12 = blk_sum4(q1a * gb2[0] + q1b * gb2[1], shr);
        float c21 = blk_sum4(q2a * ga[0] + q2b * ga[1], shr);
        float c22 = blk_sum4(q2a * gb2[0] + q2b * gb2[1], shr);
        if (t == 0) {
            a.sc[448 + b] = c11; a.sc[480 + b] = c12;
            a.sc[512 + b] = c21; a.sc[544 + b] = c22;
            a.sc[576 + b] = 1.f / s1; a.sc[608 + b] = 1.f / s2;
        }
    }
}

// ---- passX: weighted sums of x0 rows (+ optional pos pools)
__device__ void passX_dev(const KArgs& a, int blk, float* S, bool dopos) {
    int t = threadIdx.x;
    int b = blk >> 4, seg = blk & 15, l0 = seg * 32;
    const float* xb = a.x0 + ((size_t)b * Ls + l0) * Dd;
    const float* wb = a.awb + (size_t)b * Ls + l0;
    float s0 = 0.f, s1 = 0.f, s2 = 0.f;
    float p10 = 0.f, p11 = 0.f, p12 = 0.f, p20 = 0.f, p21 = 0.f, p22 = 0.f;
    for (int l = 0; l < 32; ++l) {
        float wv = wb[l];
        float x_0 = xb[(size_t)l * Dd + t];
        float x_1 = xb[(size_t)l * Dd + t + 256];
        float x_2 = xb[(size_t)l * Dd + t + 512];
        s0 += wv * x_0; s1 += wv * x_1; s2 += wv * x_2;
        if (dopos) {
            float q1 = a.pos1[(size_t)b * Ls + l0 + l], q2 = a.pos2[(size_t)b * Ls + l0 + l];
            p10 += q1 * x_0; p11 += q1 * x_1; p12 += q1 * x_2;
            p20 += q2 * x_0; p21 += q2 * x_1; p22 += q2 * x_2;
        }
    }
    atomicAdd(&S[(size_t)b * Dd + t], s0);
    atomicAdd(&S[(size_t)b * Dd + t + 256], s1);
    atomicAdd(&S[(size_t)b * Dd + t + 512], s2);
    if (dopos) {
        atomicAdd(&a.xp1[(size_t)b * Dd + t], p10);
        atomicAdd(&a.xp1[(size_t)b * Dd + t + 256], p11);
        atomicAdd(&a.xp1[(size_t)b * Dd + t + 512], p12);
        atomicAdd(&a.xp2[(size_t)b * Dd + t], p20);
        atomicAdd(&a.xp2[(size_t)b * Dd + t + 256], p21);
        atomicAdd(&a.xp2[(size_t)b * Dd + t + 512], p22);
    }
}

// ================= standalone kernels (phase = launch) =================
__global__ void k_zero_kvec(KArgs a) {
    int blk = blockIdx.x, t = threadIdx.x;
    int wv_ = t >> 6, lane = t & 63;
    for (size_t i = (size_t)blk * NTHR + t; i < (size_t)a.zcount; i += (size_t)NBLK * NTHR)
        a.zbase[i] = 0.f;
    int g = blk * 4 + wv_;
    for (int rep = 0; rep < 2; ++rep) {
        int dot = g + rep * 2048;
        if (dot < 3072) {
            int idx = dot / Dd, d = dot - idx * Dd;
            const float* row = a.kw + ((size_t)idx * Dd + d) * Dd;
            const float* swk = a.sw + (size_t)idx * 2 * Dd + Dd;
            float sA = 0.f;
            for (int j = lane; j < Dd; j += 64) sA += row[j] * swk[j];
            sA = wred(sA);
            if (lane == 0) a.kvecs[dot] = sA;
        }
    }
}

__global__ void k_gemm1(KArgs a) {
    __shared__ float As[1024], Ws[1024];
    int blk = blockIdx.x;
    sgemm_dev(a.emb, a.rel_w, a.rel_b, a.p0b, Cc, Dd, Dd, 96,
              blk % 12, (blk / 12) % 2, blk / 24, As, Ws);
}

__global__ void k_prep2(KArgs a) {
    __shared__ float As[1024], Ws[1024];
    int blk = blockIdx.x, t = threadIdx.x;
    int wv_ = t >> 6, lane = t & 63;
    if (blk < 96) {
        sgemm_dev(a.p0b, a.fc1w, nullptr, a.pp, Cc, Dd, Dd, 192,
                  blk % 12, (blk / 12) % 2, blk / 24, As, Ws);
    } else if (blk < 128) {
        int g2 = (blk - 96) * 4 + wv_;
        for (int k = 0; k < 4; ++k) {
            int j = g2 + k * 128;
            if (k == 3) { if (g2 >= 4) break; j = 384 + g2; }
            if (j >= 388) continue;
            int vv = j / Cc, r = j - vv * Cc;
            const float* va; const float* vb2 = nullptr;
            if (vv == 0) va = a.kvecs;
            else if (vv == 1) va = a.kvecs + 2 * Dd;
            else if (vv == 2) { va = a.gw + 1536; vb2 = a.gw + 2304; }
            else { va = a.gw + 4608; vb2 = a.gw + 5376; }
            const float* row = a.p0b + (size_t)r * Dd;
            float sA = 0.f;
            for (int jj = lane; jj < Dd; jj += 64)
                sA += row[jj] * (va[jj] + (vb2 ? vb2[jj] : 0.f));
            sA = wred(sA);
            if (lane == 0) a.pdots[j] = sA;
        }
    } else {
        float gs0[12], k1r[12], gs2[12], k3r[12];
#pragma unroll
        for (int k = 0; k < 12; ++k) {
            int d = lane + k * 64;
            gs0[k] = a.gw[d] + a.gw[768 + d];
            k1r[k] = a.kvecs[768 + d];
            gs2[k] = a.gw[3072 + d] + a.gw[3840 + d];
            k3r[k] = a.kvecs[2304 + d];
        }
        int gwv = (blk - 128) * 4 + wv_;
        for (int r = gwv; r < Bb * Ls; r += 1536) {
            const float* xr = a.x0 + (size_t)r * Dd;
            float s0 = 0.f, s1 = 0.f, s2 = 0.f, s3 = 0.f;
#pragma unroll
            for (int k = 0; k < 12; ++k) {
                float xv = xr[lane + k * 64];
                s0 += xv * gs0[k]; s1 += xv * k1r[k];
                s2 += xv * gs2[k]; s3 += xv * k3r[k];
            }
            s0 = wred(s0); s1 = wred(s1); s2 = wred(s2); s3 = wred(s3);
            if (lane == 0) {
                float4 o4 = make_float4(s0, s1, s2, s3);
                *(float4*)(a.xd + (size_t)r * 4) = o4;
            }
        }
    }
}

__global__ void k_attn(KArgs a, int phase) {
    __shared__ float xs[192], lw[128], shr[16];
    attn_gemv(a, phase, blockIdx.x, xs, lw, shr);
}

__global__ void k_softgate(KArgs a, int phase) {
    __shared__ float shr[16];
    softgate_dev(a, phase, blockIdx.x, shr);
}

__global__ void k_passX(KArgs a, int which) {
    passX_dev(a, blockIdx.x, which == 0 ? a.S0 : a.S1, which == 0);
}

__global__ void k_mm0(KArgs a) {
    __shared__ float xs[192], shr[16];
    mm_dev(a, blockIdx.x, a.S0, 2.f, a.avx1, a.sc + 320, 1.f, nullptr, nullptr, 0.f,
           a.vw + (size_t)1 * Dd * Dd, a.vb + Dd, a.av1,
           3, a.gw + 1536, nullptr, a.kvecs + 2 * Dd, a.gw + 4608, a.gw + 5376,
           a.sc + 128, xs, shr);
}

__global__ void k_mm1ge(KArgs a) {
    __shared__ float xs[192], xs2[192], shr[16];
    int blk = blockIdx.x;
    if (blk < 384)
        mm_dev(a, blk, a.S1, 4.f, a.avx1, a.sc + 352, 2.f, a.avx2, a.sc + 384, 1.f,
               a.vw + (size_t)3 * Dd * Dd, a.vb + 3 * Dd, a.av2,
               1, a.gw + 4608, nullptr, nullptr, nullptr, nullptr,
               a.sc + 288, xs, shr);
    if (blk >= 128) ge_dev(a, blk - 128, xs, xs2);
}

__global__ void k_aw(KArgs a) {
    __shared__ float xs[192], shr[16];
    int blk = blockIdx.x;
    if (blk < 384)
        mm_dev(a, blk, a.av1, 1.f, nullptr, nullptr, 0.f, nullptr, nullptr, 0.f,
               a.fc1w, nullptr, a.aw1, 0, nullptr, nullptr, nullptr, nullptr, nullptr,
               nullptr, xs, shr);
    else
        mm_dev(a, blk - 384, a.av2, 1.f, nullptr, nullptr, 0.f, nullptr, nullptr, 0.f,
               a.fc1w, nullptr, a.aw2, 0, nullptr, nullptr, nullptr, nullptr, nullptr,
               nullptr, xs, shr);
}

__global__ void k_logits(KArgs a) {
    __shared__ float shr[16];
    int blk = blockIdx.x, t = threadIdx.x;
    for (int r = blk; r < Bb * Cc; r += NBLK) {
        int b = r / Cc, c = r - b * Cc;
        float g1 = a.g1buf[r];
        float g2 = sigm(2.f * a.pdots[291 + c] + g1 * a.sc[192 + b] + a.sc[288 + b] + a.gb[3]);
        float ssum = 0.f;
#pragma unroll
        for (int sseg = 0; sseg < 3; ++sseg) {
            int d = t + sseg * 256;
            float h = tanhf(4.f * a.pp[(size_t)c * Dd + d]
                          + 2.f * g1 * a.aw1[(size_t)b * Dd + d]
                          + g2 * a.aw2[(size_t)b * Dd + d]
                          + a.geb[(size_t)b * Dd + d]);
            ssum += h * a.fc2w[d];
        }
        float tt = blk_sum4(ssum, shr);
        if (t == 0) a.out[r] = sigm(tt + a.fc2b[0]);
    }
}

__global__ void k_argmax(KArgs a) {
    int t = threadIdx.x;
    if (t < Bb) {
        const float* row = a.out + (size_t)t * Cc;
        float best = row[0];
        int bi = 0;
        for (int c = 1; c < Cc; ++c) {
            float v = row[c];
            if (v > best) { best = v; bi = c; }
        }
        a.out[Bb * Cc + t] = (float)bi;
    }
}

extern "C" void kernel_launch(void* const* d_in, const int* in_sizes, int n_in,
                              void* d_out, int out_size, void* d_ws, size_t ws_size,
                              hipStream_t stream) {
    KArgs ka;
    ka.x0    = (const float*)d_in[0];
    ka.pos1  = (const float*)d_in[1];
    ka.pos2  = (const float*)d_in[2];
    ka.mask  = (const int*)d_in[3];
    ka.emb   = (const float*)d_in[4];
    ka.rel_w = (const float*)d_in[5];
    ka.rel_b = (const float*)d_in[6];
    // qw(7), qb(8) dead (softmax shift-invariance); kb(10), sb(14) dead (row-constant)
    ka.kw    = (const float*)d_in[9];
    ka.vw    = (const float*)d_in[11];
    ka.vb    = (const float*)d_in[12];
    ka.sw    = (const float*)d_in[13];
    ka.gw    = (const float*)d_in[15];
    ka.gb    = (const float*)d_in[16];
    ka.fc1w  = (const float*)d_in[17];
    ka.fc1b  = (const float*)d_in[18];
    ka.fc2w  = (const float*)d_in[19];
    ka.fc2b  = (const float*)d_in[20];
    ka.out   = (float*)d_out;

    float* ws = (float*)d_ws;
    size_t off = 0;
    const size_t PD = (size_t)Cc * Dd;
    const size_t BD = (size_t)Bb * Dd;
    ka.p0b  = ws + off; off += PD;
    ka.pp   = ws + off; off += PD;
    ka.sc   = ws + off; off += 640;
    ka.avx1 = ws + off; off += BD;
    ka.avx2 = ws + off; off += BD;
    ka.av1  = ws + off; off += BD;
    ka.av2  = ws + off; off += BD;
    ka.aw1  = ws + off; off += BD;
    ka.aw2  = ws + off; off += BD;
    ka.S0   = ws + off; off += BD;
    ka.S1   = ws + off; off += BD;
    ka.xp1  = ws + off; off += BD;
    ka.xp2  = ws + off; off += BD;
    ka.geb  = ws + off; off += BD;
    ka.zbase = ws;
    ka.zcount = (int)off;
    ka.kvecs = ws + off; off += (size_t)4 * Dd;
    ka.pdots = ws + off; off += 388;
    ka.g1buf = ws + off; off += (size_t)Bb * Cc;
    ka.xd    = ws + off; off += (size_t)Bb * Ls * 4;
    ka.gx1   = ws + off; off += (size_t)Bb * Ls;
    ka.gx2   = ws + off; off += (size_t)Bb * Ls;
    ka.awb   = ws + off; off += (size_t)Bb * Ls;

    k_zero_kvec<<<NBLK, NTHR, 0, stream>>>(ka);
    k_gemm1<<<192, NTHR, 0, stream>>>(ka);
    k_prep2<<<NBLK, NTHR, 0, stream>>>(ka);
    k_attn<<<384, NTHR, 0, stream>>>(ka, 0);
    k_softgate<<<32, NTHR, 0, stream>>>(ka, 0);
    k_passX<<<NBLK, NTHR, 0, stream>>>(ka, 0);
    k_mm0<<<384, NTHR, 0, stream>>>(ka);
    k_attn<<<384, NTHR, 0, stream>>>(ka, 1);
    k_softgate<<<32, NTHR, 0, stream>>>(ka, 1);
    k_passX<<<NBLK, NTHR, 0, stream>>>(ka, 1);
    k_mm1ge<<<NBLK, NTHR, 0, stream>>>(ka);
    k_aw<<<768, NTHR, 0, stream>>>(ka);
    k_logits<<<NBLK, NTHR, 0, stream>>>(ka);
    k_argmax<<<1, 64, 0, stream>>>(ka);
}

// Round 7
// 339.368 us; speedup vs baseline: 2.9956x; 1.1312x over previous
//
#include <hip/hip_runtime.h>
#include <math.h>

#define NBLK 512
#define NTHR 256
static const int Bb = 32, Ls = 512, Dd = 768, Cc = 97;

struct KArgs {
    const float *x0, *pos1, *pos2;
    const int* mask;
    const float *emb, *rel_w, *rel_b, *kw, *vw, *vb, *sw, *gw, *gb;
    const float *fc1w, *fc1b, *fc2w, *fc2b;
    float* out;
    float *p0b, *pp, *sc, *avx1, *avx2, *av1, *av2, *aw1, *aw2, *S0, *S1, *xp1, *xp2, *geb;
    float *kvecs, *pdots, *g1buf, *xd, *gx1, *gx2, *awb;
    float* zbase;
    int zcount;
};

__device__ __forceinline__ float sigm(float x) { return 1.f / (1.f + expf(-x)); }

__device__ __forceinline__ float wred(float v) {
#pragma unroll
    for (int o = 32; o > 0; o >>= 1) v += __shfl_down(v, o, 64);
    return v;
}

__device__ __forceinline__ float blk_sum4(float v, float* shr) {
    v = wred(v);
    int t = threadIdx.x;
    if ((t & 63) == 0) shr[t >> 6] = v;
    __syncthreads();
    float r = shr[0] + shr[1] + shr[2] + shr[3];
    __syncthreads();
    return r;
}

// ---- split-K SGEMM tile: C += A[:,kb:kb+KC]@W[kb:kb+KC,:] (+bias at bz==0); C pre-zeroed
__device__ void sgemm_dev(const float* __restrict__ A, const float* __restrict__ W,
                          const float* __restrict__ bias, float* __restrict__ C,
                          int M, int N, int K, int KC, int bx, int by, int bz,
                          float* As, float* Ws) {
    int tid = threadIdx.x;
    int tx = tid & 15, ty = tid >> 4;
    int bn = bx * 64, bm = by * 64;
    int kb = bz * KC;
    int arow = tid >> 2, akq = (tid & 3) << 2;
    int wrow = tid >> 4, wcol = (tid & 15) << 2;
    int gar = bm + arow;
    bool aval = gar < M;
    const float* Ap = A + (size_t)gar * K + kb + akq;
    const float* Wp = W + (size_t)(kb + wrow) * N + bn + wcol;
    float acc[4][4] = {{0.f}};
    float4 a4 = make_float4(0.f, 0.f, 0.f, 0.f);
    if (aval) a4 = *(const float4*)Ap;
    float4 w4 = *(const float4*)Wp;
    for (int k0 = 0; k0 < KC; k0 += 16) {
        __syncthreads();
        As[(akq + 0) * 64 + arow] = a4.x; As[(akq + 1) * 64 + arow] = a4.y;
        As[(akq + 2) * 64 + arow] = a4.z; As[(akq + 3) * 64 + arow] = a4.w;
        *(float4*)&Ws[wrow * 64 + wcol] = w4;
        __syncthreads();
        if (k0 + 16 < KC) {
            if (aval) a4 = *(const float4*)(Ap + k0 + 16);
            w4 = *(const float4*)(Wp + (size_t)(k0 + 16) * N);
        }
#pragma unroll
        for (int kk = 0; kk < 16; ++kk) {
            float4 a = *(const float4*)&As[kk * 64 + (ty << 2)];
            float4 b = *(const float4*)&Ws[kk * 64 + (tx << 2)];
            acc[0][0]+=a.x*b.x; acc[0][1]+=a.x*b.y; acc[0][2]+=a.x*b.z; acc[0][3]+=a.x*b.w;
            acc[1][0]+=a.y*b.x; acc[1][1]+=a.y*b.y; acc[1][2]+=a.y*b.z; acc[1][3]+=a.y*b.w;
            acc[2][0]+=a.z*b.x; acc[2][1]+=a.z*b.y; acc[2][2]+=a.z*b.z; acc[2][3]+=a.z*b.w;
            acc[3][0]+=a.w*b.x; acc[3][1]+=a.w*b.y; acc[3][2]+=a.w*b.z; acc[3][3]+=a.w*b.w;
        }
    }
    int gc = bn + (tx << 2);
    float4 bz4 = make_float4(0.f, 0.f, 0.f, 0.f);
    if (bz == 0 && bias) bz4 = *(const float4*)(bias + gc);
#pragma unroll
    for (int i = 0; i < 4; ++i) {
        int gr = bm + (ty << 2) + i;
        if (gr < M) {
            float* cp = C + (size_t)gr * N + gc;
            atomicAdd(cp + 0, acc[i][0] + bz4.x); atomicAdd(cp + 1, acc[i][1] + bz4.y);
            atomicAdd(cp + 2, acc[i][2] + bz4.z); atomicAdd(cp + 3, acc[i][3] + bz4.w);
        }
    }
}

// ---- fused relation-attention + V-GEMV bank; jlin in [0,768): jt%3, b, kseg/96
__device__ void attn_gemv(const KArgs& a, int phase, int jlin,
                          float* xs, float* lw, float* shr) {
    int t = threadIdx.x;
    int jt = jlin % 3, b = (jlin / 3) % 32, kseg = jlin / 96;
    float v = -3.0e38f, g1 = 0.f;
    if (t < Cc) {
        if (phase == 0) v = a.pdots[t];
        else {
            g1 = sigm(a.pdots[194 + t] + a.sc[128 + b] + a.gb[1]);
            v = 2.f * a.pdots[97 + t] + g1 * a.sc[160 + b];
        }
    }
    if (phase == 1 && jt == 0 && kseg == 0 && t < Cc) a.g1buf[(size_t)b * Cc + t] = g1;
    float m = v;
#pragma unroll
    for (int o = 32; o > 0; o >>= 1) m = fmaxf(m, __shfl_down(m, o, 64));
    if ((t & 63) == 0) shr[t >> 6] = m;
    __syncthreads();
    m = fmaxf(fmaxf(shr[0], shr[1]), fmaxf(shr[2], shr[3]));
    __syncthreads();
    float e = (t < Cc) ? expf(v - m) : 0.f;
    float s = blk_sum4(e, shr);
    float wc = e / s;
    if (t < Cc) lw[t] = wc;
    float cg1 = blk_sum4(wc * g1, shr);   // publishes lw
    float alpha = (phase == 0) ? 1.f : 2.f;
    if (t < 96) {
        int d = kseg * 96 + t;
        const float* pc = a.p0b + d;
        float acc2 = 0.f;
#pragma unroll 4
        for (int c = 0; c < Cc; ++c) acc2 += lw[c] * pc[(size_t)c * Dd];
        float val = alpha * acc2;
        if (phase == 1) val += cg1 * a.av1[(size_t)b * Dd + d];
        xs[t] = val;
    }
    __syncthreads();
    const float* W = a.vw + (size_t)(phase == 0 ? 0 : 2) * Dd * Dd;
    const float* bias = a.vb + (phase == 0 ? 0 : 2) * Dd;
    float* outp = (phase == 0) ? a.avx1 : a.avx2;
    int j = jt * 256 + t;
    float acc = (kseg == 0) ? bias[j] : 0.f;
    const float* wp = W + (size_t)(kseg * 96) * Dd + j;
#pragma unroll 8
    for (int dd = 0; dd < 96; ++dd) acc += xs[dd] * wp[(size_t)dd * Dd];
    atomicAdd(&outp[(size_t)b * Dd + j], acc);
    const float* da[4]; const float* db[4]; int nd; float* dout;
    if (phase == 0) {
        da[0]=a.gw;          db[0]=nullptr;
        da[1]=a.kvecs+Dd;    db[1]=nullptr;
        da[2]=a.gw+3072;     db[2]=a.gw+3840;
        da[3]=a.kvecs+3*Dd;  db[3]=nullptr;
        nd = 4; dout = a.sc;
    } else {
        da[0]=a.gw+3072;     db[0]=nullptr;
        da[1]=a.kvecs+3*Dd;  db[1]=nullptr;
        nd = 2; dout = a.sc + 224;
    }
    for (int vv = 0; vv < nd; ++vv) {
        float wv = da[vv][j] + (db[vv] ? db[vv][j] : 0.f);
        float p = blk_sum4(acc * wv, shr);
        if (t == 0) atomicAdd(&dout[vv * 32 + b], p);
    }
}

// ---- GEMV bank: out[b,:] += xs@Wseg; xs = gamma*S + multA*coefA[b]*avA + multB*coefB[b]*avB
__device__ void mm_dev(const KArgs& a, int jlin, const float* S, float gamma,
                       const float* avA, const float* coefA, float multA,
                       const float* avB, const float* coefB, float multB,
                       const float* W, const float* bias, float* outp,
                       int ndots, const float* d0a, const float* d0b,
                       const float* d1a, const float* d2a, const float* d2b,
                       float* dout, float* xs, float* shr) {
    int t = threadIdx.x;
    int jt = jlin % 3, b = (jlin / 3) % 32, kseg = jlin / 96;
    if (t < 96) {
        int d = kseg * 96 + t;
        float v = gamma * S[(size_t)b * Dd + d];
        if (avA) v += multA * coefA[b] * avA[(size_t)b * Dd + d];
        if (avB) v += multB * coefB[b] * avB[(size_t)b * Dd + d];
        xs[t] = v;
    }
    __syncthreads();
    int j = jt * 256 + t;
    float acc = (kseg == 0 && bias) ? bias[j] : 0.f;
    const float* wp = W + (size_t)(kseg * 96) * Dd + j;
#pragma unroll 8
    for (int dd = 0; dd < 96; ++dd) acc += xs[dd] * wp[(size_t)dd * Dd];
    atomicAdd(&outp[(size_t)b * Dd + j], acc);
    if (ndots > 0) {
        float wv = d0a[j] + (d0b ? d0b[j] : 0.f);
        float p = blk_sum4(acc * wv, shr);
        if (t == 0) atomicAdd(&dout[b], p);
    }
    if (ndots > 1) {
        float p = blk_sum4(acc * d1a[j], shr);
        if (t == 0) atomicAdd(&dout[32 + b], p);
    }
    if (ndots > 2) {
        float wv = d2a[j] + (d2b ? d2b[j] : 0.f);
        float p = blk_sum4(acc * wv, shr);
        if (t == 0) atomicAdd(&dout[64 + b], p);
    }
}

// ---- ge bank: geb[b,:] += e1@W1seg + e2@W2seg (+fc1b at kseg 0)
__device__ void ge_dev(const KArgs& a, int jlin, float* xs, float* xs2) {
    int t = threadIdx.x;
    int jt = jlin % 3, b = (jlin / 3) % 32, kseg = jlin / 96;
    if (t < 96) {
        int d = kseg * 96 + t;
        float a1 = a.avx1[(size_t)b * Dd + d], a2 = a.avx2[(size_t)b * Dd + d];
        xs[t]  = (4.f * a.xp1[(size_t)b * Dd + d] + 2.f * a.sc[448 + b] * a1 + a.sc[480 + b] * a2) * a.sc[576 + b];
        xs2[t] = (4.f * a.xp2[(size_t)b * Dd + d] + 2.f * a.sc[512 + b] * a1 + a.sc[544 + b] * a2) * a.sc[608 + b];
    }
    __syncthreads();
    int j = jt * 256 + t;
    float a1 = 0.f, a2 = 0.f;
    const float* w1 = a.fc1w + (size_t)(Dd + kseg * 96) * Dd + j;
    const float* w2 = a.fc1w + (size_t)(2 * Dd + kseg * 96) * Dd + j;
#pragma unroll 8
    for (int dd = 0; dd < 96; ++dd) {
        a1 += xs[dd] * w1[(size_t)dd * Dd];
        a2 += xs2[dd] * w2[(size_t)dd * Dd];
    }
    float res = a1 + a2 + (kseg == 0 ? a.fc1b[j] : 0.f);
    atomicAdd(&a.geb[(size_t)b * Dd + j], res);
}

// ---- dual bank sharing fc1w0: aw1 += av1@W, aw2 += av2@W (one W read)
__device__ void aw_dual_dev(const KArgs& a, int jlin, float* xs, float* xs2) {
    int t = threadIdx.x;
    int jt = jlin % 3, b = (jlin / 3) % 32, kseg = jlin / 96;
    if (t < 96) {
        int d = kseg * 96 + t;
        xs[t]  = a.av1[(size_t)b * Dd + d];
        xs2[t] = a.av2[(size_t)b * Dd + d];
    }
    __syncthreads();
    int j = jt * 256 + t;
    float a1 = 0.f, a2 = 0.f;
    const float* wp = a.fc1w + (size_t)(kseg * 96) * Dd + j;
#pragma unroll 8
    for (int dd = 0; dd < 96; ++dd) {
        float w = wp[(size_t)dd * Dd];
        a1 += xs[dd] * w;
        a2 += xs2[dd] * w;
    }
    atomicAdd(&a.aw1[(size_t)b * Dd + j], a1);
    atomicAdd(&a.aw2[(size_t)b * Dd + j], a2);
}

// ---- softgate: gate coeffs + masked softmax over L (+ pool coeffs at phase 1)
__device__ void softgate_dev(const KArgs& a, int phase, int b, float* shr) {
    int t = threadIdx.x;
    float ks[2], ga[2] = {0.f, 0.f}, gb2[2] = {0.f, 0.f};
#pragma unroll
    for (int i = 0; i < 2; ++i) {
        int l = t + (i << 8);
        size_t r = (size_t)b * Ls + l;
        float4 x = *(const float4*)(a.xd + r * 4);
        if (phase == 0) {
            float g = sigm(x.x + a.sc[b] + a.gb[0]);
            a.gx1[r] = g;
            ga[i] = g;
            ks[i] = 2.f * x.y + g * a.sc[32 + b];
        } else {
            float gp = a.gx1[r];
            float g = sigm(2.f * x.z + gp * a.sc[64 + b] + a.sc[224 + b] + a.gb[2]);
            a.gx2[r] = g;
            ga[i] = gp; gb2[i] = g;
            ks[i] = 4.f * x.w + 2.f * gp * a.sc[96 + b] + g * a.sc[256 + b];
        }
        if (a.mask[r] == 0) ks[i] = -1e9f;
    }
    float mx = fmaxf(ks[0], ks[1]);
#pragma unroll
    for (int o = 32; o > 0; o >>= 1) mx = fmaxf(mx, __shfl_down(mx, o, 64));
    if ((t & 63) == 0) shr[t >> 6] = mx;
    __syncthreads();
    mx = fmaxf(fmaxf(shr[0], shr[1]), fmaxf(shr[2], shr[3]));
    __syncthreads();
    float e0 = expf(ks[0] - mx), e1 = expf(ks[1] - mx);
    float s = blk_sum4(e0 + e1, shr);
    float inv = 1.f / s;
    float w0 = e0 * inv, w1 = e1 * inv;
    a.awb[(size_t)b * Ls + t] = w0;
    a.awb[(size_t)b * Ls + t + 256] = w1;
    float ca = blk_sum4(w0 * ga[0] + w1 * ga[1], shr);
    if (phase == 0) {
        if (t == 0) a.sc[320 + b] = ca;
    } else {
        if (t == 0) a.sc[352 + b] = ca;
        float cb = blk_sum4(w0 * gb2[0] + w1 * gb2[1], shr);
        if (t == 0) a.sc[384 + b] = cb;
        float q1a = a.pos1[(size_t)b * Ls + t], q1b = a.pos1[(size_t)b * Ls + t + 256];
        float q2a = a.pos2[(size_t)b * Ls + t], q2b = a.pos2[(size_t)b * Ls + t + 256];
        float s1 = blk_sum4(q1a + q1b, shr);
        float s2 = blk_sum4(q2a + q2b, shr);
        float c11 = blk_sum4(q1a * ga[0] + q1b * ga[1], shr);
        float c12 = blk_sum4(q1a * gb2[0] + q1b * gb2[1], shr);
        float c21 = blk_sum4(q2a * ga[0] + q2b * ga[1], shr);
        float c22 = blk_sum4(q2a * gb2[0] + q2b * gb2[1], shr);
        if (t == 0) {
            a.sc[448 + b] = c11; a.sc[480 + b] = c12;
            a.sc[512 + b] = c21; a.sc[544 + b] = c22;
            a.sc[576 + b] = 1.f / s1; a.sc[608 + b] = 1.f / s2;
        }
    }
}

// ---- passX: weighted sums of x0 rows (float4 lanes, t<192)
__device__ void passX_dev(const KArgs& a, int blk, float* S, bool dopos) {
    int t = threadIdx.x;
    if (t >= 192) return;
    int b = blk >> 4, seg = blk & 15, l0 = seg * 32;
    int d4 = t << 2;
    const float* xb = a.x0 + ((size_t)b * Ls + l0) * Dd + d4;
    const float* wb = a.awb + (size_t)b * Ls + l0;
    float4 as = make_float4(0.f,0.f,0.f,0.f);
    float4 a1 = make_float4(0.f,0.f,0.f,0.f);
    float4 a2 = make_float4(0.f,0.f,0.f,0.f);
    for (int l = 0; l < 32; ++l) {
        float4 xv = *(const float4*)(xb + (size_t)l * Dd);
        float wv = wb[l];
        as.x += wv*xv.x; as.y += wv*xv.y; as.z += wv*xv.z; as.w += wv*xv.w;
        if (dopos) {
            float q1 = a.pos1[(size_t)b * Ls + l0 + l], q2 = a.pos2[(size_t)b * Ls + l0 + l];
            a1.x += q1*xv.x; a1.y += q1*xv.y; a1.z += q1*xv.z; a1.w += q1*xv.w;
            a2.x += q2*xv.x; a2.y += q2*xv.y; a2.z += q2*xv.z; a2.w += q2*xv.w;
        }
    }
    float* ds = S + (size_t)b * Dd + d4;
    atomicAdd(ds+0, as.x); atomicAdd(ds+1, as.y); atomicAdd(ds+2, as.z); atomicAdd(ds+3, as.w);
    if (dopos) {
        float* d1 = a.xp1 + (size_t)b * Dd + d4;
        float* d2 = a.xp2 + (size_t)b * Dd + d4;
        atomicAdd(d1+0, a1.x); atomicAdd(d1+1, a1.y); atomicAdd(d1+2, a1.z); atomicAdd(d1+3, a1.w);
        atomicAdd(d2+0, a2.x); atomicAdd(d2+1, a2.y); atomicAdd(d2+2, a2.z); atomicAdd(d2+3, a2.w);
    }
}

// ================= kernels =================
__global__ __launch_bounds__(NTHR) void k_zero_kvec(KArgs a) {
    int blk = blockIdx.x, t = threadIdx.x;
    int wv_ = t >> 6, lane = t & 63;
    for (size_t i = (size_t)blk * NTHR + t; i < (size_t)a.zcount; i += (size_t)NBLK * NTHR)
        a.zbase[i] = 0.f;
    int g = blk * 4 + wv_;
    for (int rep = 0; rep < 2; ++rep) {
        int dot = g + rep * 2048;
        if (dot < 3072) {
            int idx = dot / Dd, d = dot - idx * Dd;
            const float* row = a.kw + ((size_t)idx * Dd + d) * Dd;
            const float* swk = a.sw + (size_t)idx * 2 * Dd + Dd;
            float sA = 0.f;
            for (int j = lane; j < Dd; j += 64) sA += row[j] * swk[j];
            sA = wred(sA);
            if (lane == 0) a.kvecs[dot] = sA;
        }
    }
}

__global__ __launch_bounds__(NTHR) void k_gemm1(KArgs a) {
    __shared__ float As[1024], Ws[1024];
    int blk = blockIdx.x;
    sgemm_dev(a.emb, a.rel_w, a.rel_b, a.p0b, Cc, Dd, Dd, 96,
              blk % 12, (blk / 12) % 2, blk / 24, As, Ws);
}

__global__ __launch_bounds__(NTHR) void k_prep2(KArgs a) {
    __shared__ float As[1024], Ws[1024];
    int blk = blockIdx.x, t = threadIdx.x;
    int wv_ = t >> 6, lane = t & 63;
    if (blk < 96) {
        sgemm_dev(a.p0b, a.fc1w, nullptr, a.pp, Cc, Dd, Dd, 192,
                  blk % 12, (blk / 12) % 2, blk / 24, As, Ws);
    } else if (blk < 128) {
        int g2 = (blk - 96) * 4 + wv_;
        for (int k = 0; k < 4; ++k) {
            int j = g2 + k * 128;
            if (k == 3) { if (g2 >= 4) break; j = 384 + g2; }
            if (j >= 388) continue;
            int vv = j / Cc, r = j - vv * Cc;
            const float* va; const float* vb2 = nullptr;
            if (vv == 0) va = a.kvecs;
            else if (vv == 1) va = a.kvecs + 2 * Dd;
            else if (vv == 2) { va = a.gw + 1536; vb2 = a.gw + 2304; }
            else { va = a.gw + 4608; vb2 = a.gw + 5376; }
            const float* row = a.p0b + (size_t)r * Dd;
            float sA = 0.f;
            for (int jj = lane; jj < Dd; jj += 64)
                sA += row[jj] * (va[jj] + (vb2 ? vb2[jj] : 0.f));
            sA = wred(sA);
            if (lane == 0) a.pdots[j] = sA;
        }
    } else {
        // xdots: wave-per-row, float4 lanes; vectors pre-loaded in registers
        float4 gs0[3], k1r[3], gs2[3], k3r[3];
#pragma unroll
        for (int k = 0; k < 3; ++k) {
            int d = (lane << 2) + k * 256;
            float4 ga = *(const float4*)(a.gw + d);
            float4 gbv = *(const float4*)(a.gw + 768 + d);
            gs0[k] = make_float4(ga.x+gbv.x, ga.y+gbv.y, ga.z+gbv.z, ga.w+gbv.w);
            k1r[k] = *(const float4*)(a.kvecs + 768 + d);
            float4 g2a = *(const float4*)(a.gw + 3072 + d);
            float4 g2b = *(const float4*)(a.gw + 3840 + d);
            gs2[k] = make_float4(g2a.x+g2b.x, g2a.y+g2b.y, g2a.z+g2b.z, g2a.w+g2b.w);
            k3r[k] = *(const float4*)(a.kvecs + 2304 + d);
        }
        int gwv = (blk - 128) * 4 + wv_;
        for (int r = gwv; r < Bb * Ls; r += 1536) {
            const float* xr = a.x0 + (size_t)r * Dd;
            float s0 = 0.f, s1 = 0.f, s2 = 0.f, s3 = 0.f;
#pragma unroll
            for (int k = 0; k < 3; ++k) {
                float4 xv = *(const float4*)(xr + (lane << 2) + k * 256);
                s0 += xv.x*gs0[k].x + xv.y*gs0[k].y + xv.z*gs0[k].z + xv.w*gs0[k].w;
                s1 += xv.x*k1r[k].x + xv.y*k1r[k].y + xv.z*k1r[k].z + xv.w*k1r[k].w;
                s2 += xv.x*gs2[k].x + xv.y*gs2[k].y + xv.z*gs2[k].z + xv.w*gs2[k].w;
                s3 += xv.x*k3r[k].x + xv.y*k3r[k].y + xv.z*k3r[k].z + xv.w*k3r[k].w;
            }
            s0 = wred(s0); s1 = wred(s1); s2 = wred(s2); s3 = wred(s3);
            if (lane == 0) {
                float4 o4 = make_float4(s0, s1, s2, s3);
                *(float4*)(a.xd + (size_t)r * 4) = o4;
            }
        }
    }
}

__global__ __launch_bounds__(NTHR) void k_attn(KArgs a, int phase) {
    __shared__ float xs[96], lw[128], shr[16];
    attn_gemv(a, phase, blockIdx.x, xs, lw, shr);
}

__global__ __launch_bounds__(NTHR) void k_softgate(KArgs a, int phase) {
    __shared__ float shr[16];
    softgate_dev(a, phase, blockIdx.x, shr);
}

__global__ __launch_bounds__(NTHR) void k_passX0(KArgs a) {
    passX_dev(a, blockIdx.x, a.S0, true);
}

__global__ __launch_bounds__(NTHR) void k_mm0(KArgs a) {
    __shared__ float xs[96], shr[16];
    mm_dev(a, blockIdx.x, a.S0, 2.f, a.avx1, a.sc + 320, 1.f, nullptr, nullptr, 0.f,
           a.vw + (size_t)1 * Dd * Dd, a.vb + Dd, a.av1,
           3, a.gw + 1536, nullptr, a.kvecs + 2 * Dd, a.gw + 4608, a.gw + 5376,
           a.sc + 128, xs, shr);
}

// passX1 (512 blocks) || ge bank (768 blocks)
__global__ __launch_bounds__(NTHR) void k_passX1ge(KArgs a) {
    __shared__ float xs[96], xs2[96];
    int blk = blockIdx.x;
    if (blk < 512) passX_dev(a, blk, a.S1, false);
    else ge_dev(a, blk - 512, xs, xs2);
}

__global__ __launch_bounds__(NTHR) void k_mm1(KArgs a) {
    __shared__ float xs[96], shr[16];
    mm_dev(a, blockIdx.x, a.S1, 4.f, a.avx1, a.sc + 352, 2.f, a.avx2, a.sc + 384, 1.f,
           a.vw + (size_t)3 * Dd * Dd, a.vb + 3 * Dd, a.av2,
           1, a.gw + 4608, nullptr, nullptr, nullptr, nullptr,
           a.sc + 288, xs, shr);
}

__global__ __launch_bounds__(NTHR) void k_awdual(KArgs a) {
    __shared__ float xs[96], xs2[96];
    aw_dual_dev(a, blockIdx.x, xs, xs2);
}

__global__ __launch_bounds__(NTHR) void k_logits(KArgs a) {
    __shared__ float shr[16];
    int blk = blockIdx.x, t = threadIdx.x;
    for (int r = blk; r < Bb * Cc; r += NBLK) {
        int b = r / Cc, c = r - b * Cc;
        float g1 = a.g1buf[r];
        float g2 = sigm(2.f * a.pdots[291 + c] + g1 * a.sc[192 + b] + a.sc[288 + b] + a.gb[3]);
        float ssum = 0.f;
#pragma unroll
        for (int sseg = 0; sseg < 3; ++sseg) {
            int d = t + sseg * 256;
            float h = tanhf(4.f * a.pp[(size_t)c * Dd + d]
                          + 2.f * g1 * a.aw1[(size_t)b * Dd + d]
                          + g2 * a.aw2[(size_t)b * Dd + d]
                          + a.geb[(size_t)b * Dd + d]);
            ssum += h * a.fc2w[d];
        }
        float tt = blk_sum4(ssum, shr);
        if (t == 0) a.out[r] = sigm(tt + a.fc2b[0]);
    }
}

__global__ void k_argmax(KArgs a) {
    int t = threadIdx.x;
    if (t < Bb) {
        const float* row = a.out + (size_t)t * Cc;
        float best = row[0];
        int bi = 0;
        for (int c = 1; c < Cc; ++c) {
            float v = row[c];
            if (v > best) { best = v; bi = c; }
        }
        a.out[Bb * Cc + t] = (float)bi;
    }
}

extern "C" void kernel_launch(void* const* d_in, const int* in_sizes, int n_in,
                              void* d_out, int out_size, void* d_ws, size_t ws_size,
                              hipStream_t stream) {
    KArgs ka;
    ka.x0    = (const float*)d_in[0];
    ka.pos1  = (const float*)d_in[1];
    ka.pos2  = (const float*)d_in[2];
    ka.mask  = (const int*)d_in[3];
    ka.emb   = (const float*)d_in[4];
    ka.rel_w = (const float*)d_in[5];
    ka.rel_b = (const float*)d_in[6];
    // qw(7), qb(8) dead (softmax shift-invariance); kb(10), sb(14) dead (row-constant)
    ka.kw    = (const float*)d_in[9];
    ka.vw    = (const float*)d_in[11];
    ka.vb    = (const float*)d_in[12];
    ka.sw    = (const float*)d_in[13];
    ka.gw    = (const float*)d_in[15];
    ka.gb    = (const float*)d_in[16];
    ka.fc1w  = (const float*)d_in[17];
    ka.fc1b  = (const float*)d_in[18];
    ka.fc2w  = (const float*)d_in[19];
    ka.fc2b  = (const float*)d_in[20];
    ka.out   = (float*)d_out;

    float* ws = (float*)d_ws;
    size_t off = 0;
    const size_t PD = (size_t)Cc * Dd;
    const size_t BD = (size_t)Bb * Dd;
    ka.p0b  = ws + off; off += PD;
    ka.pp   = ws + off; off += PD;
    ka.sc   = ws + off; off += 640;
    ka.avx1 = ws + off; off += BD;
    ka.avx2 = ws + off; off += BD;
    ka.av1  = ws + off; off += BD;
    ka.av2  = ws + off; off += BD;
    ka.aw1  = ws + off; off += BD;
    ka.aw2  = ws + off; off += BD;
    ka.S0   = ws + off; off += BD;
    ka.S1   = ws + off; off += BD;
    ka.xp1  = ws + off; off += BD;
    ka.xp2  = ws + off; off += BD;
    ka.geb  = ws + off; off += BD;
    ka.zbase = ws;
    ka.zcount = (int)off;
    ka.kvecs = ws + off; off += (size_t)4 * Dd;
    ka.pdots = ws + off; off += 388;
    ka.g1buf = ws + off; off += (size_t)Bb * Cc;
    ka.xd    = ws + off; off += (size_t)Bb * Ls * 4;
    ka.gx1   = ws + off; off += (size_t)Bb * Ls;
    ka.gx2   = ws + off; off += (size_t)Bb * Ls;
    ka.awb   = ws + off; off += (size_t)Bb * Ls;

    k_zero_kvec<<<NBLK, NTHR, 0, stream>>>(ka);
    k_gemm1<<<192, NTHR, 0, stream>>>(ka);
    k_prep2<<<NBLK, NTHR, 0, stream>>>(ka);
    k_attn<<<768, NTHR, 0, stream>>>(ka, 0);
    k_softgate<<<32, NTHR, 0, stream>>>(ka, 0);
    k_passX0<<<NBLK, NTHR, 0, stream>>>(ka);
    k_mm0<<<768, NTHR, 0, stream>>>(ka);
    k_attn<<<768, NTHR, 0, stream>>>(ka, 1);
    k_softgate<<<32, NTHR, 0, stream>>>(ka, 1);
    k_passX1ge<<<1280, NTHR, 0, stream>>>(ka);
    k_mm1<<<768, NTHR, 0, stream>>>(ka);
    k_awdual<<<768, NTHR, 0, stream>>>(ka);
    k_logits<<<NBLK, NTHR, 0, stream>>>(ka);
    k_argmax<<<1, 64, 0, stream>>>(ka);
}